// Round 1
// baseline (1809.568 us; speedup 1.0000x reference)
//
#include <hip/hip_runtime.h>
#include <hip/hip_bf16.h>

typedef unsigned short u16;
typedef unsigned int u32;
typedef __attribute__((ext_vector_type(8))) short short8;
typedef __attribute__((ext_vector_type(8))) unsigned short ushort8v;
typedef __attribute__((ext_vector_type(4))) unsigned short ushort4v;
typedef __attribute__((ext_vector_type(4))) float f32x4;

static constexpr int B_ = 2, S_ = 4096, D_ = 1024, H_ = 16, HG_ = 2, W_ = 128, DFF_ = 4096;
static constexpr int HL_ = H_ - HG_;   // 14 local heads
static constexpr int M_ = B_ * S_;     // 8192 rows

static __device__ __forceinline__ u16 f2b(float f) {
    u32 u = __builtin_bit_cast(u32, f);
    u32 r = (u + 0x7fffu + ((u >> 16) & 1u)) >> 16;   // RNE
    return (u16)r;
}
static __device__ __forceinline__ float b2f(u16 b) {
    return __builtin_bit_cast(float, (u32)b << 16);
}

// ---------------- f32 -> bf16 convert (vectorized) ----------------
__global__ __launch_bounds__(256) void k_f32_to_bf16(const float* __restrict__ src,
                                                     u16* __restrict__ dst, int n4) {
    int i = blockIdx.x * 256 + threadIdx.x;
    if (i >= n4) return;
    float4 v = reinterpret_cast<const float4*>(src)[i];
    ushort4v o; o[0] = f2b(v.x); o[1] = f2b(v.y); o[2] = f2b(v.z); o[3] = f2b(v.w);
    reinterpret_cast<ushort4v*>(dst)[i] = o;
}

// ---------------- weight transpose+convert: W[K][N] f32 -> WT[ro+N][K] bf16 ----------------
__global__ __launch_bounds__(256) void k_transpose_bf16(const float* __restrict__ src,
                                                        u16* __restrict__ dst,
                                                        int K, int N, int ro) {
    __shared__ float tile[32][33];
    const int tx = threadIdx.x & 31, ty = threadIdx.x >> 5;  // 32x8
    const int bx = blockIdx.x, by = blockIdx.y;
#pragma unroll
    for (int jj = 0; jj < 4; ++jj) {
        int kk = by * 32 + ty + jj * 8;
        int nn = bx * 32 + tx;
        tile[ty + jj * 8][tx] = src[(size_t)kk * N + nn];
    }
    __syncthreads();
#pragma unroll
    for (int jj = 0; jj < 4; ++jj) {
        int nn = bx * 32 + ty + jj * 8;
        int kk = by * 32 + tx;
        dst[(size_t)(ro + nn) * K + kk] = f2b(tile[tx][ty + jj * 8]);
    }
}

__global__ void k_pack_bias3(const float* __restrict__ a, const float* __restrict__ b,
                             const float* __restrict__ c, float* __restrict__ dst) {
    int i = blockIdx.x * 256 + threadIdx.x;
    if (i >= 3072) return;
    dst[i] = i < 1024 ? a[i] : (i < 2048 ? b[i - 1024] : c[i - 2048]);
}

// ---------------- bf16 MFMA GEMM: C[M,N] = A[M,K] @ Bt[N,K]^T + bias ----------------
// m97 structure: 128x128 tile, BK=32, 4 waves (2x2), 4x4 frags/wave, global_load_lds(16B).
#define GLDS16(gp, lp) __builtin_amdgcn_global_load_lds( \
    (const __attribute__((address_space(1))) void*)(gp),  \
    (__attribute__((address_space(3))) void*)(lp), 16, 0, 0)

template <bool LEAKY, bool OUTF, bool OUTB>
__global__ __launch_bounds__(256) void k_gemm(const u16* __restrict__ A, const u16* __restrict__ Bt,
                                              const float* __restrict__ bias,
                                              float* __restrict__ Cf, u16* __restrict__ Cb,
                                              int M, int N, int K) {
    __shared__ __align__(16) u16 lA[128 * 32];
    __shared__ __align__(16) u16 lB[128 * 32];
    const int tid = threadIdx.x;
    const int lane = tid & 63, wave = tid >> 6;
    const int wr = wave >> 1, wc = wave & 1;
    const int m0 = blockIdx.x * 128, n0 = blockIdx.y * 128;

    f32x4 acc[4][4];
#pragma unroll
    for (int i = 0; i < 4; ++i)
#pragma unroll
        for (int j = 0; j < 4; ++j)
#pragma unroll
            for (int e = 0; e < 4; ++e) acc[i][j][e] = 0.f;

    const int arow = tid >> 2;            // 0..63
    const int acol = (tid & 3) * 8;       // 0,8,16,24
    const int koff = (lane >> 4) * 8;
    const int rbase = wr * 64 + (lane & 15);
    const int cbase = wc * 64 + (lane & 15);

    for (int k0 = 0; k0 < K; k0 += 32) {
        __syncthreads();
        {
            const u16* ga0 = A + (size_t)(m0 + arow) * K + k0 + acol;
            const u16* ga1 = A + (size_t)(m0 + 64 + arow) * K + k0 + acol;
            GLDS16(ga0, lA + wave * 512);
            GLDS16(ga1, lA + 2048 + wave * 512);
            const u16* gb0 = Bt + (size_t)(n0 + arow) * K + k0 + acol;
            const u16* gb1 = Bt + (size_t)(n0 + 64 + arow) * K + k0 + acol;
            GLDS16(gb0, lB + wave * 512);
            GLDS16(gb1, lB + 2048 + wave * 512);
        }
        __syncthreads();

        short8 af[4], bfr[4];
#pragma unroll
        for (int mi = 0; mi < 4; ++mi)
            af[mi] = *reinterpret_cast<const short8*>(&lA[(rbase + mi * 16) * 32 + koff]);
#pragma unroll
        for (int ni = 0; ni < 4; ++ni)
            bfr[ni] = *reinterpret_cast<const short8*>(&lB[(cbase + ni * 16) * 32 + koff]);
#pragma unroll
        for (int mi = 0; mi < 4; ++mi)
#pragma unroll
            for (int ni = 0; ni < 4; ++ni)
                acc[mi][ni] = __builtin_amdgcn_mfma_f32_16x16x32_bf16(af[mi], bfr[ni], acc[mi][ni], 0, 0, 0);
    }

#pragma unroll
    for (int mi = 0; mi < 4; ++mi) {
        const int rowb = m0 + wr * 64 + mi * 16 + (lane >> 4) * 4;
#pragma unroll
        for (int ni = 0; ni < 4; ++ni) {
            const int col = n0 + wc * 64 + ni * 16 + (lane & 15);
            const float bs = bias[col];
#pragma unroll
            for (int j = 0; j < 4; ++j) {
                float v = acc[mi][ni][j] + bs;
                if (LEAKY) v = v > 0.f ? v : 0.2f * v;
                const size_t idx = (size_t)(rowb + j) * N + col;
                if (OUTF) Cf[idx] = v;
                if (OUTB) Cb[idx] = f2b(v);
            }
        }
    }
}

// ---------------- flash attention (vector f32), 8 query rows/block (2 per wave) ----------------
// qkv: bf16 [8192][3072]  (Q cols 0..1023, K 1024..2047, V 2048..3071; head h at h*64)
// WINDOW>0: banded (local); WINDOW==0: full (global, + mask*(-1000))
template <int WINDOW>
__global__ __launch_bounds__(256) void k_attn(const u16* __restrict__ qkv,
                                              const float* __restrict__ mask,
                                              u16* __restrict__ out, int hbase) {
    __shared__ float Kl[64][65];
    __shared__ float Vl[64][65];
    __shared__ float ql[8][64];
    __shared__ float pl[4][64];
    const int tid = threadIdx.x, lane = tid & 63, wave = tid >> 6;
    const int b = blockIdx.z, h = hbase + blockIdx.y;
    const int r0 = blockIdx.x * 8;
    const float scale = 0.125f;  // 1/sqrt(64)

#pragma unroll
    for (int it = 0; it < 2; ++it) {  // stage 8 q rows, pre-scaled
        int e = it * 256 + tid;
        ql[e >> 6][e & 63] = b2f(qkv[(size_t)(b * S_ + r0 + (e >> 6)) * 3072 + h * 64 + (e & 63)]) * scale;
    }

    float m[2] = {-1e30f, -1e30f}, lsum[2] = {0.f, 0.f}, accd[2] = {0.f, 0.f};
    int t_lo, t_hi;
    if (WINDOW > 0) { t_lo = max(0, r0 - WINDOW) >> 6; t_hi = min(S_ - 1, r0 + 7 + WINDOW) >> 6; }
    else            { t_lo = 0; t_hi = S_ / 64 - 1; }

    for (int t = t_lo; t <= t_hi; ++t) {
        __syncthreads();
#pragma unroll
        for (int it = 0; it < 2; ++it) {  // stage K,V tile: 64 rows x 64 dims
            int e = (it * 256 + tid) * 8;
            int kr = e >> 6, kc = e & 63;
            size_t rowoff = (size_t)(b * S_ + t * 64 + kr) * 3072 + h * 64;
            ushort8v k8 = *reinterpret_cast<const ushort8v*>(&qkv[rowoff + 1024 + kc]);
            ushort8v v8 = *reinterpret_cast<const ushort8v*>(&qkv[rowoff + 2048 + kc]);
#pragma unroll
            for (int u = 0; u < 8; ++u) { Kl[kr][kc + u] = b2f(k8[u]); Vl[kr][kc + u] = b2f(v8[u]); }
        }
        __syncthreads();
        const int j = t * 64 + lane;
        float mterm = 0.f;
        if (WINDOW == 0) mterm = mask[b * S_ + j] * (-1000.0f);
#pragma unroll
        for (int rr = 0; rr < 2; ++rr) {
            const int i = r0 + rr * 4 + wave;
            float s = 0.f;
#pragma unroll
            for (int d = 0; d < 64; ++d) s = fmaf(ql[rr * 4 + wave][d], Kl[lane][d], s);
            s += mterm;
            bool valid = (WINDOW == 0) || (j >= i - WINDOW && j <= i + WINDOW);
            s = valid ? s : -1e30f;
            float tm = s;
#pragma unroll
            for (int off = 32; off >= 1; off >>= 1) tm = fmaxf(tm, __shfl_xor(tm, off));
            if (tm > -1e29f) {   // tile has at least one valid key for this row (wave-uniform)
                float mn = fmaxf(m[rr], tm);
                float fac = __expf(m[rr] - mn);
                float p = __expf(s - mn);   // s=-1e30 -> 0
                pl[wave][lane] = p;
                float ps = p;
#pragma unroll
                for (int off = 32; off >= 1; off >>= 1) ps += __shfl_xor(ps, off);
                lsum[rr] = lsum[rr] * fac + ps;
                m[rr] = mn;
                float a = accd[rr] * fac;
#pragma unroll
                for (int j2 = 0; j2 < 64; ++j2) a = fmaf(pl[wave][j2], Vl[j2][lane], a);
                accd[rr] = a;
            }
        }
    }
#pragma unroll
    for (int rr = 0; rr < 2; ++rr) {
        const int i = r0 + rr * 4 + wave;
        out[(size_t)(b * S_ + i) * 1024 + h * 64 + lane] = f2b(accd[rr] / lsum[rr]);
    }
}

// ---------------- fused residual + LayerNorm (row = 1024) ----------------
__global__ __launch_bounds__(256) void k_ln(const float* __restrict__ base, const float* __restrict__ delta,
                                            const float* __restrict__ g, const float* __restrict__ bt,
                                            float* __restrict__ outf, u16* __restrict__ outb) {
    __shared__ float red[8];
    const int row = blockIdx.x, tid = threadIdx.x;
    const int lane = tid & 63, wave = tid >> 6;
    float4 xb = reinterpret_cast<const float4*>(base + (size_t)row * 1024)[tid];
    float4 xd = reinterpret_cast<const float4*>(delta + (size_t)row * 1024)[tid];
    float x0 = xb.x + xd.x, x1 = xb.y + xd.y, x2 = xb.z + xd.z, x3 = xb.w + xd.w;
    float s = x0 + x1 + x2 + x3;
#pragma unroll
    for (int off = 32; off >= 1; off >>= 1) s += __shfl_xor(s, off);
    if (lane == 0) red[wave] = s;
    __syncthreads();
    float mu = (red[0] + red[1] + red[2] + red[3]) * (1.f / 1024.f);
    float d0 = x0 - mu, d1 = x1 - mu, d2 = x2 - mu, d3 = x3 - mu;
    float s2 = d0 * d0 + d1 * d1 + d2 * d2 + d3 * d3;
#pragma unroll
    for (int off = 32; off >= 1; off >>= 1) s2 += __shfl_xor(s2, off);
    if (lane == 0) red[4 + wave] = s2;
    __syncthreads();
    float var = (red[4] + red[5] + red[6] + red[7]) * (1.f / 1024.f);
    float rs = rsqrtf(var + 1e-6f);
    float4 gv = reinterpret_cast<const float4*>(g)[tid];
    float4 bv = reinterpret_cast<const float4*>(bt)[tid];
    float o0 = d0 * rs * gv.x + bv.x;
    float o1 = d1 * rs * gv.y + bv.y;
    float o2 = d2 * rs * gv.z + bv.z;
    float o3 = d3 * rs * gv.w + bv.w;
    if (outf) {
        float4 ov; ov.x = o0; ov.y = o1; ov.z = o2; ov.w = o3;
        reinterpret_cast<float4*>(outf + (size_t)row * 1024)[tid] = ov;
    }
    if (outb) {
        ushort4v ob; ob[0] = f2b(o0); ob[1] = f2b(o1); ob[2] = f2b(o2); ob[3] = f2b(o3);
        reinterpret_cast<ushort4v*>(outb + (size_t)row * 1024)[tid] = ob;
    }
}

extern "C" void kernel_launch(void* const* d_in, const int* in_sizes, int n_in,
                              void* d_out, int out_size, void* d_ws, size_t ws_size,
                              hipStream_t stream) {
    const float* x    = (const float*)d_in[0];
    const float* mask = (const float*)d_in[1];
    const float* wq   = (const float*)d_in[2];
    const float* wq_b = (const float*)d_in[3];
    const float* wk   = (const float*)d_in[4];
    const float* wk_b = (const float*)d_in[5];
    const float* wv   = (const float*)d_in[6];
    const float* wv_b = (const float*)d_in[7];
    const float* wo   = (const float*)d_in[8];
    const float* wo_b = (const float*)d_in[9];
    const float* w1   = (const float*)d_in[10];
    const float* b1   = (const float*)d_in[11];
    const float* w2   = (const float*)d_in[12];
    const float* b2   = (const float*)d_in[13];
    const float* ln1g = (const float*)d_in[14];
    const float* ln1b = (const float*)d_in[15];
    const float* ln2g = (const float*)d_in[16];
    const float* ln2b = (const float*)d_in[17];
    float* out = (float*)d_out;

    char* ws = (char*)d_ws;
    const size_t MB = 1024ull * 1024ull;
    // P0 [0,64MB): qkv bf16 (48MB), later FFN hidden bf16 (64MB)
    u16*   qkv_b  = (u16*)(ws + 0);
    u16*   h_b    = (u16*)(ws + 0);
    // P1 [64,96MB): wo-out f32, later ffn2-out f32
    float* ybuf   = (float*)(ws + 64 * MB);
    // P2 [96,128MB): out1 f32 (long-lived)
    float* out1   = (float*)(ws + 96 * MB);
    // P3 [128,144MB): x bf16 -> attn bf16 -> out1 bf16 (sequential lifetimes)
    u16*   xb     = (u16*)(ws + 128 * MB);
    u16*   attn_b = (u16*)(ws + 128 * MB);
    u16*   out1_b = (u16*)(ws + 128 * MB);
    // P4 [144,152MB): transposed weights bf16 (max 8MB), sequential lifetimes
    u16*   wT     = (u16*)(ws + 144 * MB);
    // P5 [152MB,+12KB): packed qkv bias f32
    float* bias3  = (float*)(ws + 152 * MB);

    const dim3 tb(256);

    // x -> bf16
    k_f32_to_bf16<<<(M_ * D_ / 4 + 255) / 256, tb, 0, stream>>>(x, xb, M_ * D_ / 4);
    // pack W_qkv^T bf16 [3072][1024] + bias
    k_transpose_bf16<<<dim3(32, 32), tb, 0, stream>>>(wq, wT, 1024, 1024, 0);
    k_transpose_bf16<<<dim3(32, 32), tb, 0, stream>>>(wk, wT, 1024, 1024, 1024);
    k_transpose_bf16<<<dim3(32, 32), tb, 0, stream>>>(wv, wT, 1024, 1024, 2048);
    k_pack_bias3<<<12, tb, 0, stream>>>(wq_b, wk_b, wv_b, bias3);
    // QKV: [8192,3072] bf16
    k_gemm<false, false, true><<<dim3(M_ / 128, 3072 / 128), tb, 0, stream>>>(
        xb, wT, bias3, nullptr, qkv_b, M_, 3072, 1024);
    // attention -> attn_b bf16 [B,S,H,64]
    k_attn<W_><<<dim3(S_ / 8, HL_, B_), tb, 0, stream>>>(qkv_b, mask, attn_b, 0);
    k_attn<0><<<dim3(S_ / 8, HG_, B_), tb, 0, stream>>>(qkv_b, mask, attn_b, HL_);
    // output projection
    k_transpose_bf16<<<dim3(32, 32), tb, 0, stream>>>(wo, wT, 1024, 1024, 0);
    k_gemm<false, true, false><<<dim3(M_ / 128, 1024 / 128), tb, 0, stream>>>(
        attn_b, wT, wo_b, ybuf, nullptr, M_, 1024, 1024);
    // LN1 (residual x)
    k_ln<<<M_, tb, 0, stream>>>(x, ybuf, ln1g, ln1b, out1, out1_b);
    // FFN1 (leaky relu 0.2)
    k_transpose_bf16<<<dim3(128, 32), tb, 0, stream>>>(w1, wT, 1024, 4096, 0);
    k_gemm<true, false, true><<<dim3(M_ / 128, 4096 / 128), tb, 0, stream>>>(
        out1_b, wT, b1, nullptr, h_b, M_, 4096, 1024);
    // FFN2
    k_transpose_bf16<<<dim3(32, 128), tb, 0, stream>>>(w2, wT, 4096, 1024, 0);
    k_gemm<false, true, false><<<dim3(M_ / 128, 1024 / 128), tb, 0, stream>>>(
        h_b, wT, b2, ybuf, nullptr, M_, 1024, 4096);
    // LN2 (residual out1) -> final output f32
    k_ln<<<M_, tb, 0, stream>>>(out1, ybuf, ln2g, ln2b, out, nullptr);
}

// Round 2
// 544.786 us; speedup vs baseline: 3.3216x; 3.3216x over previous
//
#include <hip/hip_runtime.h>
#include <hip/hip_bf16.h>

typedef unsigned short u16;
typedef unsigned int u32;
typedef __attribute__((ext_vector_type(8))) short short8;
typedef __attribute__((ext_vector_type(8))) unsigned short ushort8v;
typedef __attribute__((ext_vector_type(4))) unsigned short ushort4v;
typedef __attribute__((ext_vector_type(4))) float f32x4;

static constexpr int B_ = 2, S_ = 4096, D_ = 1024, H_ = 16, HG_ = 2, W_ = 128, DFF_ = 4096;
static constexpr int HL_ = H_ - HG_;   // 14 local heads
static constexpr int M_ = B_ * S_;     // 8192 rows

static __device__ __forceinline__ u16 f2b(float f) {
    u32 u = __builtin_bit_cast(u32, f);
    u32 r = (u + 0x7fffu + ((u >> 16) & 1u)) >> 16;   // RNE
    return (u16)r;
}
static __device__ __forceinline__ float b2f(u16 b) {
    return __builtin_bit_cast(float, (u32)b << 16);
}

// ---------------- f32 -> bf16 convert (vectorized) ----------------
__global__ __launch_bounds__(256) void k_f32_to_bf16(const float* __restrict__ src,
                                                     u16* __restrict__ dst, int n4) {
    int i = blockIdx.x * 256 + threadIdx.x;
    if (i >= n4) return;
    float4 v = reinterpret_cast<const float4*>(src)[i];
    ushort4v o; o[0] = f2b(v.x); o[1] = f2b(v.y); o[2] = f2b(v.z); o[3] = f2b(v.w);
    reinterpret_cast<ushort4v*>(dst)[i] = o;
}

// ---------------- weight transpose+convert: W[K][N] f32 -> WT[ro+N][K] bf16 ----------------
__global__ __launch_bounds__(256) void k_transpose_bf16(const float* __restrict__ src,
                                                        u16* __restrict__ dst,
                                                        int K, int N, int ro) {
    __shared__ float tile[32][33];
    const int tx = threadIdx.x & 31, ty = threadIdx.x >> 5;  // 32x8
    const int bx = blockIdx.x, by = blockIdx.y;
#pragma unroll
    for (int jj = 0; jj < 4; ++jj) {
        int kk = by * 32 + ty + jj * 8;
        int nn = bx * 32 + tx;
        tile[ty + jj * 8][tx] = src[(size_t)kk * N + nn];
    }
    __syncthreads();
#pragma unroll
    for (int jj = 0; jj < 4; ++jj) {
        int nn = bx * 32 + ty + jj * 8;
        int kk = by * 32 + tx;
        dst[(size_t)(ro + nn) * K + kk] = f2b(tile[tx][ty + jj * 8]);
    }
}

// ---------------- V transpose: qkv V-cols -> vT[(b*H+h)*64 + d][S] bf16 ----------------
__global__ __launch_bounds__(256) void k_transpose_v(const u16* __restrict__ qkv,
                                                     u16* __restrict__ vT) {
    __shared__ u16 tile[32][33];
    const int tx = threadIdx.x & 31, ty = threadIdx.x >> 5;  // 32x8
    const int s0 = blockIdx.x * 32;
    const int d0 = blockIdx.y * 32;
    const int bh = blockIdx.z;
    const int b = bh >> 4, h = bh & 15;
#pragma unroll
    for (int jj = 0; jj < 4; ++jj) {
        int srow = s0 + ty + jj * 8;
        tile[ty + jj * 8][tx] = qkv[(size_t)(b * S_ + srow) * 3072 + 2048 + h * 64 + d0 + tx];
    }
    __syncthreads();
#pragma unroll
    for (int jj = 0; jj < 4; ++jj) {
        int d = d0 + ty + jj * 8;
        vT[(size_t)((b * H_ + h) * 64 + d) * S_ + s0 + tx] = tile[tx][ty + jj * 8];
    }
}

__global__ void k_pack_bias3(const float* __restrict__ a, const float* __restrict__ b,
                             const float* __restrict__ c, float* __restrict__ dst) {
    int i = blockIdx.x * 256 + threadIdx.x;
    if (i >= 3072) return;
    dst[i] = i < 1024 ? a[i] : (i < 2048 ? b[i - 1024] : c[i - 2048]);
}

// ---------------- bf16 MFMA GEMM: C[M,N] = A[M,K] @ Bt[N,K]^T + bias ----------------
#define GLDS16(gp, lp) __builtin_amdgcn_global_load_lds( \
    (const __attribute__((address_space(1))) void*)(gp),  \
    (__attribute__((address_space(3))) void*)(lp), 16, 0, 0)

template <bool LEAKY, bool OUTF, bool OUTB>
__global__ __launch_bounds__(256) void k_gemm(const u16* __restrict__ A, const u16* __restrict__ Bt,
                                              const float* __restrict__ bias,
                                              float* __restrict__ Cf, u16* __restrict__ Cb,
                                              int M, int N, int K) {
    __shared__ __align__(16) u16 lA[128 * 32];
    __shared__ __align__(16) u16 lB[128 * 32];
    const int tid = threadIdx.x;
    const int lane = tid & 63, wave = tid >> 6;
    const int wr = wave >> 1, wc = wave & 1;
    const int m0 = blockIdx.x * 128, n0 = blockIdx.y * 128;

    f32x4 acc[4][4];
#pragma unroll
    for (int i = 0; i < 4; ++i)
#pragma unroll
        for (int j = 0; j < 4; ++j)
#pragma unroll
            for (int e = 0; e < 4; ++e) acc[i][j][e] = 0.f;

    const int arow = tid >> 2;
    const int acol = (tid & 3) * 8;
    const int koff = (lane >> 4) * 8;
    const int rbase = wr * 64 + (lane & 15);
    const int cbase = wc * 64 + (lane & 15);

    for (int k0 = 0; k0 < K; k0 += 32) {
        __syncthreads();
        {
            const u16* ga0 = A + (size_t)(m0 + arow) * K + k0 + acol;
            const u16* ga1 = A + (size_t)(m0 + 64 + arow) * K + k0 + acol;
            GLDS16(ga0, lA + wave * 512);
            GLDS16(ga1, lA + 2048 + wave * 512);
            const u16* gb0 = Bt + (size_t)(n0 + arow) * K + k0 + acol;
            const u16* gb1 = Bt + (size_t)(n0 + 64 + arow) * K + k0 + acol;
            GLDS16(gb0, lB + wave * 512);
            GLDS16(gb1, lB + 2048 + wave * 512);
        }
        __syncthreads();

        short8 af[4], bfr[4];
#pragma unroll
        for (int mi = 0; mi < 4; ++mi)
            af[mi] = *reinterpret_cast<const short8*>(&lA[(rbase + mi * 16) * 32 + koff]);
#pragma unroll
        for (int ni = 0; ni < 4; ++ni)
            bfr[ni] = *reinterpret_cast<const short8*>(&lB[(cbase + ni * 16) * 32 + koff]);
#pragma unroll
        for (int mi = 0; mi < 4; ++mi)
#pragma unroll
            for (int ni = 0; ni < 4; ++ni)
                acc[mi][ni] = __builtin_amdgcn_mfma_f32_16x16x32_bf16(af[mi], bfr[ni], acc[mi][ni], 0, 0, 0);
    }

#pragma unroll
    for (int mi = 0; mi < 4; ++mi) {
        const int rowb = m0 + wr * 64 + mi * 16 + (lane >> 4) * 4;
#pragma unroll
        for (int ni = 0; ni < 4; ++ni) {
            const int col = n0 + wc * 64 + ni * 16 + (lane & 15);
            const float bs = bias[col];
#pragma unroll
            for (int j = 0; j < 4; ++j) {
                float v = acc[mi][ni][j] + bs;
                if (LEAKY) v = v > 0.f ? v : 0.2f * v;
                const size_t idx = (size_t)(rowb + j) * N + col;
                if (OUTF) Cf[idx] = v;
                if (OUTB) Cb[idx] = f2b(v);
            }
        }
    }
}

// ---------------- MFMA flash attention ----------------
// Swapped layout: per wave, 16 q-rows; S^T tile = mfma(K_frag, Q_frag) so each
// lane's regs hold one q-row (col = lane&15). PV computed as O^T = mfma(Vt_frag, P_frag).
// qkv: bf16 [8192][3072]; vT: bf16 [(b*H+h)*64 + d][4096].
// WINDOW>0: banded local heads; WINDOW==0: full attention + mask*(-1000).
template <int WINDOW>
__global__ __launch_bounds__(256) void k_attn_mfma(const u16* __restrict__ qkv,
                                                   const u16* __restrict__ vT,
                                                   const float* __restrict__ mask,
                                                   u16* __restrict__ out, int hbase) {
    __shared__ __align__(16) u16 Kl[64][72];      // K tile  [key][dh]
    __shared__ __align__(16) u16 Vl[64][72];      // V^T tile [d][key]
    __shared__ __align__(16) u16 Pl[4][1024];     // per-wave P [q][key], pitch 128B, swizzled
    __shared__ float maskl[64];
    const int tid = threadIdx.x, lane = tid & 63, wave = tid >> 6;
    const int c = lane & 15, g = lane >> 4;
    const int b = blockIdx.z, h = hbase + blockIdx.y;
    const int q0 = blockIdx.x * 64;
    const int qrow = q0 + wave * 16 + c;          // this lane's q (S^T col)

    short8 qf[2];
    {
        const u16* qp = qkv + (size_t)(b * S_ + qrow) * 3072 + h * 64 + g * 8;
        qf[0] = *reinterpret_cast<const short8*>(qp);
        qf[1] = *reinterpret_cast<const short8*>(qp + 32);
    }

    f32x4 acc[4];   // O^T tiles: row d = dt*16 + 4g + j, col q = c
#pragma unroll
    for (int dt = 0; dt < 4; ++dt)
#pragma unroll
        for (int j = 0; j < 4; ++j) acc[dt][j] = 0.f;
    float mrow = -1e30f, lrow = 0.f;

    int t_lo, t_hi;
    if (WINDOW > 0) { t_lo = max(0, q0 - WINDOW) >> 6; t_hi = min(S_ - 1, q0 + 63 + WINDOW) >> 6; }
    else            { t_lo = 0; t_hi = S_ / 64 - 1; }

    u16* pw = Pl[wave];

    for (int t = t_lo; t <= t_hi; ++t) {
        __syncthreads();
#pragma unroll
        for (int it = 0; it < 2; ++it) {
            int L = it * 256 + tid;                 // 0..511
            int r = L >> 3, cb = (L & 7) * 8;
            *reinterpret_cast<ushort8v*>(&Kl[r][cb]) =
                *reinterpret_cast<const ushort8v*>(&qkv[(size_t)(b * S_ + t * 64 + r) * 3072 + 1024 + h * 64 + cb]);
            *reinterpret_cast<ushort8v*>(&Vl[r][cb]) =
                *reinterpret_cast<const ushort8v*>(&vT[(size_t)((b * H_ + h) * 64 + r) * S_ + t * 64 + cb]);
        }
        if (WINDOW == 0 && tid < 64) maskl[tid] = mask[b * S_ + t * 64 + tid] * (-1000.0f);
        __syncthreads();

        // S^T[key][q] = K · Q^T  (accumulate over 2 k-chunks of dh=64)
        f32x4 s[4];
#pragma unroll
        for (int nt = 0; nt < 4; ++nt)
#pragma unroll
            for (int j = 0; j < 4; ++j) s[nt][j] = 0.f;
#pragma unroll
        for (int kc = 0; kc < 2; ++kc) {
#pragma unroll
            for (int nt = 0; nt < 4; ++nt) {
                short8 kf = *reinterpret_cast<const short8*>(&Kl[nt * 16 + c][kc * 32 + g * 8]);
                s[nt] = __builtin_amdgcn_mfma_f32_16x16x32_bf16(kf, qf[kc], s[nt], 0, 0, 0);
            }
        }

        // scale + mask + row max (row = q = c, lane-local + 2 shfl)
        float p[4][4];
        float tmax = -1e30f;
#pragma unroll
        for (int nt = 0; nt < 4; ++nt)
#pragma unroll
            for (int j = 0; j < 4; ++j) {
                float sv = s[nt][j] * 0.125f;
                if (WINDOW > 0) {
                    int key = t * 64 + nt * 16 + 4 * g + j;
                    bool val = (key >= qrow - WINDOW) && (key <= qrow + WINDOW);
                    sv = val ? sv : -1e30f;
                } else {
                    sv += maskl[nt * 16 + 4 * g + j];
                }
                p[nt][j] = sv;
                tmax = fmaxf(tmax, sv);
            }
        tmax = fmaxf(tmax, __shfl_xor(tmax, 16));
        tmax = fmaxf(tmax, __shfl_xor(tmax, 32));
        float mnew = fmaxf(mrow, tmax);
        float fac = __expf(mrow - mnew);
        mrow = mnew;
        float psum = 0.f;
#pragma unroll
        for (int nt = 0; nt < 4; ++nt)
#pragma unroll
            for (int j = 0; j < 4; ++j) {
                p[nt][j] = __expf(p[nt][j] - mnew);
                psum += p[nt][j];
            }
        lrow = lrow * fac + psum;   // partial over this lane's 16 keys
#pragma unroll
        for (int dt = 0; dt < 4; ++dt)
#pragma unroll
            for (int j = 0; j < 4; ++j) acc[dt][j] *= fac;

        // P (C/D layout) -> LDS, swizzled; lane writes its q-row c, keys nt*16+4g+{0..3}
#pragma unroll
        for (int nt = 0; nt < 4; ++nt)
#pragma unroll
            for (int jp = 0; jp < 2; ++jp) {
                u32 pk = (u32)f2b(p[nt][2 * jp]) | ((u32)f2b(p[nt][2 * jp + 1]) << 16);
                int byteoff = (c << 7) + ((nt * 32 + 8 * g + 4 * jp) ^ ((c & 7) << 4));
                *reinterpret_cast<u32*>(reinterpret_cast<char*>(pw) + byteoff) = pk;
            }
        asm volatile("s_waitcnt lgkmcnt(0)" ::: "memory");

        // PV: O^T += V^T · P   (A = Vt frag, B = P frag)
#pragma unroll
        for (int h2 = 0; h2 < 2; ++h2) {
            int rb = (c << 7) + ((h2 * 64 + g * 16) ^ ((c & 7) << 4));
            short8 pa = *reinterpret_cast<const short8*>(reinterpret_cast<char*>(pw) + rb);
#pragma unroll
            for (int dt = 0; dt < 4; ++dt) {
                short8 vf = *reinterpret_cast<const short8*>(&Vl[dt * 16 + c][h2 * 32 + g * 8]);
                acc[dt] = __builtin_amdgcn_mfma_f32_16x16x32_bf16(vf, pa, acc[dt], 0, 0, 0);
            }
        }
    }

    float lfull = lrow + __shfl_xor(lrow, 16);
    lfull += __shfl_xor(lfull, 32);
    const float rinv = 1.0f / lfull;

#pragma unroll
    for (int dt = 0; dt < 4; ++dt) {
        u32 w0 = (u32)f2b(acc[dt][0] * rinv) | ((u32)f2b(acc[dt][1] * rinv) << 16);
        u32 w1 = (u32)f2b(acc[dt][2] * rinv) | ((u32)f2b(acc[dt][3] * rinv) << 16);
        uint2 wv; wv.x = w0; wv.y = w1;
        *reinterpret_cast<uint2*>(out + (size_t)(b * S_ + qrow) * 1024 + h * 64 + dt * 16 + 4 * g) = wv;
    }
}

// ---------------- fused residual + LayerNorm (row = 1024) ----------------
__global__ __launch_bounds__(256) void k_ln(const float* __restrict__ base, const float* __restrict__ delta,
                                            const float* __restrict__ g, const float* __restrict__ bt,
                                            float* __restrict__ outf, u16* __restrict__ outb) {
    __shared__ float red[8];
    const int row = blockIdx.x, tid = threadIdx.x;
    const int lane = tid & 63, wave = tid >> 6;
    float4 xb = reinterpret_cast<const float4*>(base + (size_t)row * 1024)[tid];
    float4 xd = reinterpret_cast<const float4*>(delta + (size_t)row * 1024)[tid];
    float x0 = xb.x + xd.x, x1 = xb.y + xd.y, x2 = xb.z + xd.z, x3 = xb.w + xd.w;
    float s = x0 + x1 + x2 + x3;
#pragma unroll
    for (int off = 32; off >= 1; off >>= 1) s += __shfl_xor(s, off);
    if (lane == 0) red[wave] = s;
    __syncthreads();
    float mu = (red[0] + red[1] + red[2] + red[3]) * (1.f / 1024.f);
    float d0 = x0 - mu, d1 = x1 - mu, d2 = x2 - mu, d3 = x3 - mu;
    float s2 = d0 * d0 + d1 * d1 + d2 * d2 + d3 * d3;
#pragma unroll
    for (int off = 32; off >= 1; off >>= 1) s2 += __shfl_xor(s2, off);
    if (lane == 0) red[4 + wave] = s2;
    __syncthreads();
    float var = (red[4] + red[5] + red[6] + red[7]) * (1.f / 1024.f);
    float rs = rsqrtf(var + 1e-6f);
    float4 gv = reinterpret_cast<const float4*>(g)[tid];
    float4 bv = reinterpret_cast<const float4*>(bt)[tid];
    float o0 = d0 * rs * gv.x + bv.x;
    float o1 = d1 * rs * gv.y + bv.y;
    float o2 = d2 * rs * gv.z + bv.z;
    float o3 = d3 * rs * gv.w + bv.w;
    if (outf) {
        float4 ov; ov.x = o0; ov.y = o1; ov.z = o2; ov.w = o3;
        reinterpret_cast<float4*>(outf + (size_t)row * 1024)[tid] = ov;
    }
    if (outb) {
        ushort4v ob; ob[0] = f2b(o0); ob[1] = f2b(o1); ob[2] = f2b(o2); ob[3] = f2b(o3);
        reinterpret_cast<ushort4v*>(outb + (size_t)row * 1024)[tid] = ob;
    }
}

extern "C" void kernel_launch(void* const* d_in, const int* in_sizes, int n_in,
                              void* d_out, int out_size, void* d_ws, size_t ws_size,
                              hipStream_t stream) {
    const float* x    = (const float*)d_in[0];
    const float* mask = (const float*)d_in[1];
    const float* wq   = (const float*)d_in[2];
    const float* wq_b = (const float*)d_in[3];
    const float* wk   = (const float*)d_in[4];
    const float* wk_b = (const float*)d_in[5];
    const float* wv   = (const float*)d_in[6];
    const float* wv_b = (const float*)d_in[7];
    const float* wo   = (const float*)d_in[8];
    const float* wo_b = (const float*)d_in[9];
    const float* w1   = (const float*)d_in[10];
    const float* b1   = (const float*)d_in[11];
    const float* w2   = (const float*)d_in[12];
    const float* b2   = (const float*)d_in[13];
    const float* ln1g = (const float*)d_in[14];
    const float* ln1b = (const float*)d_in[15];
    const float* ln2g = (const float*)d_in[16];
    const float* ln2b = (const float*)d_in[17];
    float* out = (float*)d_out;

    char* ws = (char*)d_ws;
    const size_t MB = 1024ull * 1024ull;
    // P0 [0,64MB): qkv bf16 (48MB), later FFN hidden bf16 (64MB)
    u16*   qkv_b  = (u16*)(ws + 0);
    u16*   h_b    = (u16*)(ws + 0);
    // P1 [64,96MB): vT bf16 (16MB, attention phase) -> wo-out f32 / ffn2-out f32
    u16*   vTb    = (u16*)(ws + 64 * MB);
    float* ybuf   = (float*)(ws + 64 * MB);
    // P2 [96,128MB): out1 f32 (long-lived)
    float* out1   = (float*)(ws + 96 * MB);
    // P3 [128,144MB): x bf16 -> attn bf16 -> out1 bf16 (sequential lifetimes)
    u16*   xb     = (u16*)(ws + 128 * MB);
    u16*   attn_b = (u16*)(ws + 128 * MB);
    u16*   out1_b = (u16*)(ws + 128 * MB);
    // P4 [144,152MB): transposed weights bf16 (max 8MB), sequential lifetimes
    u16*   wT     = (u16*)(ws + 144 * MB);
    // P5 [152MB,+12KB): packed qkv bias f32
    float* bias3  = (float*)(ws + 152 * MB);

    const dim3 tb(256);

    // x -> bf16
    k_f32_to_bf16<<<(M_ * D_ / 4 + 255) / 256, tb, 0, stream>>>(x, xb, M_ * D_ / 4);
    // pack W_qkv^T bf16 [3072][1024] + bias
    k_transpose_bf16<<<dim3(32, 32), tb, 0, stream>>>(wq, wT, 1024, 1024, 0);
    k_transpose_bf16<<<dim3(32, 32), tb, 0, stream>>>(wk, wT, 1024, 1024, 1024);
    k_transpose_bf16<<<dim3(32, 32), tb, 0, stream>>>(wv, wT, 1024, 1024, 2048);
    k_pack_bias3<<<12, tb, 0, stream>>>(wq_b, wk_b, wv_b, bias3);
    // QKV: [8192,3072] bf16
    k_gemm<false, false, true><<<dim3(M_ / 128, 3072 / 128), tb, 0, stream>>>(
        xb, wT, bias3, nullptr, qkv_b, M_, 3072, 1024);
    // V pre-transpose for attention PV
    k_transpose_v<<<dim3(S_ / 32, 2, B_ * H_), tb, 0, stream>>>(qkv_b, vTb);
    // attention -> attn_b bf16 [B,S,H,64]
    k_attn_mfma<W_><<<dim3(S_ / 64, HL_, B_), tb, 0, stream>>>(qkv_b, vTb, mask, attn_b, 0);
    k_attn_mfma<0><<<dim3(S_ / 64, HG_, B_), tb, 0, stream>>>(qkv_b, vTb, mask, attn_b, HL_);
    // output projection
    k_transpose_bf16<<<dim3(32, 32), tb, 0, stream>>>(wo, wT, 1024, 1024, 0);
    k_gemm<false, true, false><<<dim3(M_ / 128, 1024 / 128), tb, 0, stream>>>(
        attn_b, wT, wo_b, ybuf, nullptr, M_, 1024, 1024);
    // LN1 (residual x)
    k_ln<<<M_, tb, 0, stream>>>(x, ybuf, ln1g, ln1b, out1, out1_b);
    // FFN1 (leaky relu 0.2)
    k_transpose_bf16<<<dim3(128, 32), tb, 0, stream>>>(w1, wT, 1024, 4096, 0);
    k_gemm<true, false, true><<<dim3(M_ / 128, 4096 / 128), tb, 0, stream>>>(
        out1_b, wT, b1, nullptr, h_b, M_, 4096, 1024);
    // FFN2
    k_transpose_bf16<<<dim3(32, 128), tb, 0, stream>>>(w2, wT, 4096, 1024, 0);
    k_gemm<false, true, false><<<dim3(M_ / 128, 1024 / 128), tb, 0, stream>>>(
        h_b, wT, b2, ybuf, nullptr, M_, 1024, 4096);
    // LN2 (residual out1) -> final output f32
    k_ln<<<M_, tb, 0, stream>>>(out1, ybuf, ln2g, ln2b, out, nullptr);
}

// Round 3
// 433.588 us; speedup vs baseline: 4.1735x; 1.2565x over previous
//
#include <hip/hip_runtime.h>
#include <hip/hip_bf16.h>

typedef unsigned short u16;
typedef unsigned int u32;
typedef __attribute__((ext_vector_type(8))) short short8;
typedef __attribute__((ext_vector_type(8))) unsigned short ushort8v;
typedef __attribute__((ext_vector_type(4))) unsigned short ushort4v;
typedef __attribute__((ext_vector_type(4))) float f32x4;

static constexpr int B_ = 2, S_ = 4096, D_ = 1024, H_ = 16, HG_ = 2, W_ = 128, DFF_ = 4096;
static constexpr int HL_ = H_ - HG_;   // 14 local heads
static constexpr int M_ = B_ * S_;     // 8192 rows
static constexpr int NCH_ = 4;         // KV chunks for global-head split

static __device__ __forceinline__ u16 f2b(float f) {
    u32 u = __builtin_bit_cast(u32, f);
    u32 r = (u + 0x7fffu + ((u >> 16) & 1u)) >> 16;   // RNE
    return (u16)r;
}
static __device__ __forceinline__ float b2f(u16 b) {
    return __builtin_bit_cast(float, (u32)b << 16);
}

// ---------------- f32 -> bf16 convert (vectorized) ----------------
__global__ __launch_bounds__(256) void k_f32_to_bf16(const float* __restrict__ src,
                                                     u16* __restrict__ dst, int n4) {
    int i = blockIdx.x * 256 + threadIdx.x;
    if (i >= n4) return;
    float4 v = reinterpret_cast<const float4*>(src)[i];
    ushort4v o; o[0] = f2b(v.x); o[1] = f2b(v.y); o[2] = f2b(v.z); o[3] = f2b(v.w);
    reinterpret_cast<ushort4v*>(dst)[i] = o;
}

// ---------------- weight transpose+convert: W[K][N] f32 -> WT[ro+N][K] bf16 ----------------
__global__ __launch_bounds__(256) void k_transpose_bf16(const float* __restrict__ src,
                                                        u16* __restrict__ dst,
                                                        int K, int N, int ro) {
    __shared__ float tile[32][33];
    const int tx = threadIdx.x & 31, ty = threadIdx.x >> 5;  // 32x8
    const int bx = blockIdx.x, by = blockIdx.y;
#pragma unroll
    for (int jj = 0; jj < 4; ++jj) {
        int kk = by * 32 + ty + jj * 8;
        int nn = bx * 32 + tx;
        tile[ty + jj * 8][tx] = src[(size_t)kk * N + nn];
    }
    __syncthreads();
#pragma unroll
    for (int jj = 0; jj < 4; ++jj) {
        int nn = bx * 32 + ty + jj * 8;
        int kk = by * 32 + tx;
        dst[(size_t)(ro + nn) * K + kk] = f2b(tile[tx][ty + jj * 8]);
    }
}

// ---------------- V transpose: qkv V-cols -> vT[(b*H+h)*64 + d][S] bf16 ----------------
__global__ __launch_bounds__(256) void k_transpose_v(const u16* __restrict__ qkv,
                                                     u16* __restrict__ vT) {
    __shared__ u16 tile[32][33];
    const int tx = threadIdx.x & 31, ty = threadIdx.x >> 5;  // 32x8
    const int s0 = blockIdx.x * 32;
    const int d0 = blockIdx.y * 32;
    const int bh = blockIdx.z;
    const int b = bh >> 4, h = bh & 15;
#pragma unroll
    for (int jj = 0; jj < 4; ++jj) {
        int srow = s0 + ty + jj * 8;
        tile[ty + jj * 8][tx] = qkv[(size_t)(b * S_ + srow) * 3072 + 2048 + h * 64 + d0 + tx];
    }
    __syncthreads();
#pragma unroll
    for (int jj = 0; jj < 4; ++jj) {
        int d = d0 + ty + jj * 8;
        vT[(size_t)((b * H_ + h) * 64 + d) * S_ + s0 + tx] = tile[tx][ty + jj * 8];
    }
}

__global__ void k_pack_bias3(const float* __restrict__ a, const float* __restrict__ b,
                             const float* __restrict__ c, float* __restrict__ dst) {
    int i = blockIdx.x * 256 + threadIdx.x;
    if (i >= 3072) return;
    dst[i] = i < 1024 ? a[i] : (i < 2048 ? b[i - 1024] : c[i - 2048]);
}

// ---------------- bf16 MFMA GEMM: C[M,N] = A[M,K] @ Bt[N,K]^T + bias ----------------
#define GLDS16(gp, lp) __builtin_amdgcn_global_load_lds( \
    (const __attribute__((address_space(1))) void*)(gp),  \
    (__attribute__((address_space(3))) void*)(lp), 16, 0, 0)

template <bool LEAKY, bool OUTF, bool OUTB>
__global__ __launch_bounds__(256) void k_gemm(const u16* __restrict__ A, const u16* __restrict__ Bt,
                                              const float* __restrict__ bias,
                                              float* __restrict__ Cf, u16* __restrict__ Cb,
                                              int M, int N, int K) {
    __shared__ __align__(16) u16 lA[128 * 32];
    __shared__ __align__(16) u16 lB[128 * 32];
    const int tid = threadIdx.x;
    const int lane = tid & 63, wave = tid >> 6;
    const int wr = wave >> 1, wc = wave & 1;
    const int m0 = blockIdx.x * 128, n0 = blockIdx.y * 128;

    f32x4 acc[4][4];
#pragma unroll
    for (int i = 0; i < 4; ++i)
#pragma unroll
        for (int j = 0; j < 4; ++j)
#pragma unroll
            for (int e = 0; e < 4; ++e) acc[i][j][e] = 0.f;

    const int arow = tid >> 2;
    const int acol = (tid & 3) * 8;
    const int koff = (lane >> 4) * 8;
    const int rbase = wr * 64 + (lane & 15);
    const int cbase = wc * 64 + (lane & 15);

    for (int k0 = 0; k0 < K; k0 += 32) {
        __syncthreads();
        {
            const u16* ga0 = A + (size_t)(m0 + arow) * K + k0 + acol;
            const u16* ga1 = A + (size_t)(m0 + 64 + arow) * K + k0 + acol;
            GLDS16(ga0, lA + wave * 512);
            GLDS16(ga1, lA + 2048 + wave * 512);
            const u16* gb0 = Bt + (size_t)(n0 + arow) * K + k0 + acol;
            const u16* gb1 = Bt + (size_t)(n0 + 64 + arow) * K + k0 + acol;
            GLDS16(gb0, lB + wave * 512);
            GLDS16(gb1, lB + 2048 + wave * 512);
        }
        __syncthreads();

        short8 af[4], bfr[4];
#pragma unroll
        for (int mi = 0; mi < 4; ++mi)
            af[mi] = *reinterpret_cast<const short8*>(&lA[(rbase + mi * 16) * 32 + koff]);
#pragma unroll
        for (int ni = 0; ni < 4; ++ni)
            bfr[ni] = *reinterpret_cast<const short8*>(&lB[(cbase + ni * 16) * 32 + koff]);
        __builtin_amdgcn_s_setprio(1);
#pragma unroll
        for (int mi = 0; mi < 4; ++mi)
#pragma unroll
            for (int ni = 0; ni < 4; ++ni)
                acc[mi][ni] = __builtin_amdgcn_mfma_f32_16x16x32_bf16(af[mi], bfr[ni], acc[mi][ni], 0, 0, 0);
        __builtin_amdgcn_s_setprio(0);
    }

#pragma unroll
    for (int mi = 0; mi < 4; ++mi) {
        const int rowb = m0 + wr * 64 + mi * 16 + (lane >> 4) * 4;
#pragma unroll
        for (int ni = 0; ni < 4; ++ni) {
            const int col = n0 + wc * 64 + ni * 16 + (lane & 15);
            const float bs = bias[col];
#pragma unroll
            for (int j = 0; j < 4; ++j) {
                float v = acc[mi][ni][j] + bs;
                if (LEAKY) v = v > 0.f ? v : 0.2f * v;
                const size_t idx = (size_t)(rowb + j) * N + col;
                if (OUTF) Cf[idx] = v;
                if (OUTB) Cb[idx] = f2b(v);
            }
        }
    }
}

// ---------------- MFMA flash attention, LOCAL (banded) heads ----------------
// Swapped layout: per wave, 16 q-rows; S^T tile = mfma(K_frag, Q_frag) so each
// lane's regs hold one q-row (col = lane&15). PV computed as O^T = mfma(Vt_frag, P_frag).
__global__ __launch_bounds__(256) void k_attn_local(const u16* __restrict__ qkv,
                                                    const u16* __restrict__ vT,
                                                    u16* __restrict__ out) {
    __shared__ __align__(16) u16 Kl[64][72];
    __shared__ __align__(16) u16 Vl[64][72];
    __shared__ __align__(16) u16 Pl[4][1024];
    const int tid = threadIdx.x, lane = tid & 63, wave = tid >> 6;
    const int c = lane & 15, g = lane >> 4;
    const int b = blockIdx.z, h = blockIdx.y;
    const int q0 = blockIdx.x * 64;
    const int qrow = q0 + wave * 16 + c;

    short8 qf[2];
    {
        const u16* qp = qkv + (size_t)(b * S_ + qrow) * 3072 + h * 64 + g * 8;
        qf[0] = *reinterpret_cast<const short8*>(qp);
        qf[1] = *reinterpret_cast<const short8*>(qp + 32);
    }

    f32x4 acc[4];
#pragma unroll
    for (int dt = 0; dt < 4; ++dt)
#pragma unroll
        for (int j = 0; j < 4; ++j) acc[dt][j] = 0.f;
    float mrow = -1e30f, lrow = 0.f;

    const int t_lo = max(0, q0 - W_) >> 6;
    const int t_hi = min(S_ - 1, q0 + 63 + W_) >> 6;
    u16* pw = Pl[wave];

    for (int t = t_lo; t <= t_hi; ++t) {
        __syncthreads();
#pragma unroll
        for (int it = 0; it < 2; ++it) {
            int L = it * 256 + tid;
            int r = L >> 3, cb = (L & 7) * 8;
            *reinterpret_cast<ushort8v*>(&Kl[r][cb]) =
                *reinterpret_cast<const ushort8v*>(&qkv[(size_t)(b * S_ + t * 64 + r) * 3072 + 1024 + h * 64 + cb]);
            *reinterpret_cast<ushort8v*>(&Vl[r][cb]) =
                *reinterpret_cast<const ushort8v*>(&vT[(size_t)((b * H_ + h) * 64 + r) * S_ + t * 64 + cb]);
        }
        __syncthreads();

        f32x4 s[4];
#pragma unroll
        for (int nt = 0; nt < 4; ++nt)
#pragma unroll
            for (int j = 0; j < 4; ++j) s[nt][j] = 0.f;
        __builtin_amdgcn_s_setprio(1);
#pragma unroll
        for (int kc = 0; kc < 2; ++kc) {
#pragma unroll
            for (int nt = 0; nt < 4; ++nt) {
                short8 kf = *reinterpret_cast<const short8*>(&Kl[nt * 16 + c][kc * 32 + g * 8]);
                s[nt] = __builtin_amdgcn_mfma_f32_16x16x32_bf16(kf, qf[kc], s[nt], 0, 0, 0);
            }
        }
        __builtin_amdgcn_s_setprio(0);

        float p[4][4];
        float tmax = -1e30f;
#pragma unroll
        for (int nt = 0; nt < 4; ++nt)
#pragma unroll
            for (int j = 0; j < 4; ++j) {
                float sv = s[nt][j] * 0.125f;
                int key = t * 64 + nt * 16 + 4 * g + j;
                bool val = (key >= qrow - W_) && (key <= qrow + W_);
                sv = val ? sv : -1e30f;
                p[nt][j] = sv;
                tmax = fmaxf(tmax, sv);
            }
        tmax = fmaxf(tmax, __shfl_xor(tmax, 16));
        tmax = fmaxf(tmax, __shfl_xor(tmax, 32));
        float mnew = fmaxf(mrow, tmax);
        float fac = __expf(mrow - mnew);
        mrow = mnew;
        float psum = 0.f;
#pragma unroll
        for (int nt = 0; nt < 4; ++nt)
#pragma unroll
            for (int j = 0; j < 4; ++j) {
                p[nt][j] = __expf(p[nt][j] - mnew);
                psum += p[nt][j];
            }
        lrow = lrow * fac + psum;
#pragma unroll
        for (int dt = 0; dt < 4; ++dt)
#pragma unroll
            for (int j = 0; j < 4; ++j) acc[dt][j] *= fac;

#pragma unroll
        for (int nt = 0; nt < 4; ++nt)
#pragma unroll
            for (int jp = 0; jp < 2; ++jp) {
                u32 pk = (u32)f2b(p[nt][2 * jp]) | ((u32)f2b(p[nt][2 * jp + 1]) << 16);
                int byteoff = (c << 7) + ((nt * 32 + 8 * g + 4 * jp) ^ ((c & 7) << 4));
                *reinterpret_cast<u32*>(reinterpret_cast<char*>(pw) + byteoff) = pk;
            }
        asm volatile("s_waitcnt lgkmcnt(0)" ::: "memory");

        __builtin_amdgcn_s_setprio(1);
#pragma unroll
        for (int h2 = 0; h2 < 2; ++h2) {
            int rb = (c << 7) + ((h2 * 64 + g * 16) ^ ((c & 7) << 4));
            short8 pa = *reinterpret_cast<const short8*>(reinterpret_cast<char*>(pw) + rb);
#pragma unroll
            for (int dt = 0; dt < 4; ++dt) {
                short8 vf = *reinterpret_cast<const short8*>(&Vl[dt * 16 + c][h2 * 32 + g * 8]);
                acc[dt] = __builtin_amdgcn_mfma_f32_16x16x32_bf16(vf, pa, acc[dt], 0, 0, 0);
            }
        }
        __builtin_amdgcn_s_setprio(0);
    }

    float lfull = lrow + __shfl_xor(lrow, 16);
    lfull += __shfl_xor(lfull, 32);
    const float rinv = 1.0f / lfull;

#pragma unroll
    for (int dt = 0; dt < 4; ++dt) {
        u32 w0 = (u32)f2b(acc[dt][0] * rinv) | ((u32)f2b(acc[dt][1] * rinv) << 16);
        u32 w1 = (u32)f2b(acc[dt][2] * rinv) | ((u32)f2b(acc[dt][3] * rinv) << 16);
        uint2 wv; wv.x = w0; wv.y = w1;
        *reinterpret_cast<uint2*>(out + (size_t)(b * S_ + qrow) * 1024 + h * 64 + dt * 16 + 4 * g) = wv;
    }
}

// ---------------- GLOBAL heads: split-KV partial flash ----------------
// grid (S/64, HG*NCH, B). Each block: 64 q rows, KV chunk of 16 tiles.
// Writes unnormalized partial O in [q][d] f32 layout + per-row (m, l).
__global__ __launch_bounds__(256) void k_attn_global_part(const u16* __restrict__ qkv,
                                                          const u16* __restrict__ vT,
                                                          const float* __restrict__ mask,
                                                          float* __restrict__ po,
                                                          float* __restrict__ ml) {
    __shared__ __align__(16) u16 Kl[64][72];
    __shared__ __align__(16) u16 Vl[64][72];
    __shared__ __align__(16) u16 Pl[4][1024];
    __shared__ float maskl[64];
    const int tid = threadIdx.x, lane = tid & 63, wave = tid >> 6;
    const int c = lane & 15, g = lane >> 4;
    const int b = blockIdx.z;
    const int hh = blockIdx.y >> 2, ch = blockIdx.y & 3;
    const int h = HL_ + hh;
    const int q0 = blockIdx.x * 64;
    const int qrow = q0 + wave * 16 + c;

    short8 qf[2];
    {
        const u16* qp = qkv + (size_t)(b * S_ + qrow) * 3072 + h * 64 + g * 8;
        qf[0] = *reinterpret_cast<const short8*>(qp);
        qf[1] = *reinterpret_cast<const short8*>(qp + 32);
    }

    f32x4 acc[4];
#pragma unroll
    for (int dt = 0; dt < 4; ++dt)
#pragma unroll
        for (int j = 0; j < 4; ++j) acc[dt][j] = 0.f;
    float mrow = -1e30f, lrow = 0.f;
    u16* pw = Pl[wave];

    const int t_lo = ch * (S_ / 64 / NCH_), t_hi = t_lo + (S_ / 64 / NCH_) - 1;
    for (int t = t_lo; t <= t_hi; ++t) {
        __syncthreads();
#pragma unroll
        for (int it = 0; it < 2; ++it) {
            int L = it * 256 + tid;
            int r = L >> 3, cb = (L & 7) * 8;
            *reinterpret_cast<ushort8v*>(&Kl[r][cb]) =
                *reinterpret_cast<const ushort8v*>(&qkv[(size_t)(b * S_ + t * 64 + r) * 3072 + 1024 + h * 64 + cb]);
            *reinterpret_cast<ushort8v*>(&Vl[r][cb]) =
                *reinterpret_cast<const ushort8v*>(&vT[(size_t)((b * H_ + h) * 64 + r) * S_ + t * 64 + cb]);
        }
        if (tid < 64) maskl[tid] = mask[b * S_ + t * 64 + tid] * (-1000.0f);
        __syncthreads();

        f32x4 s[4];
#pragma unroll
        for (int nt = 0; nt < 4; ++nt)
#pragma unroll
            for (int j = 0; j < 4; ++j) s[nt][j] = 0.f;
        __builtin_amdgcn_s_setprio(1);
#pragma unroll
        for (int kc = 0; kc < 2; ++kc) {
#pragma unroll
            for (int nt = 0; nt < 4; ++nt) {
                short8 kf = *reinterpret_cast<const short8*>(&Kl[nt * 16 + c][kc * 32 + g * 8]);
                s[nt] = __builtin_amdgcn_mfma_f32_16x16x32_bf16(kf, qf[kc], s[nt], 0, 0, 0);
            }
        }
        __builtin_amdgcn_s_setprio(0);

        float p[4][4];
        float tmax = -1e30f;
#pragma unroll
        for (int nt = 0; nt < 4; ++nt)
#pragma unroll
            for (int j = 0; j < 4; ++j) {
                float sv = s[nt][j] * 0.125f + maskl[nt * 16 + 4 * g + j];
                p[nt][j] = sv;
                tmax = fmaxf(tmax, sv);
            }
        tmax = fmaxf(tmax, __shfl_xor(tmax, 16));
        tmax = fmaxf(tmax, __shfl_xor(tmax, 32));
        float mnew = fmaxf(mrow, tmax);
        float fac = __expf(mrow - mnew);
        mrow = mnew;
        float psum = 0.f;
#pragma unroll
        for (int nt = 0; nt < 4; ++nt)
#pragma unroll
            for (int j = 0; j < 4; ++j) {
                p[nt][j] = __expf(p[nt][j] - mnew);
                psum += p[nt][j];
            }
        lrow = lrow * fac + psum;
#pragma unroll
        for (int dt = 0; dt < 4; ++dt)
#pragma unroll
            for (int j = 0; j < 4; ++j) acc[dt][j] *= fac;

#pragma unroll
        for (int nt = 0; nt < 4; ++nt)
#pragma unroll
            for (int jp = 0; jp < 2; ++jp) {
                u32 pk = (u32)f2b(p[nt][2 * jp]) | ((u32)f2b(p[nt][2 * jp + 1]) << 16);
                int byteoff = (c << 7) + ((nt * 32 + 8 * g + 4 * jp) ^ ((c & 7) << 4));
                *reinterpret_cast<u32*>(reinterpret_cast<char*>(pw) + byteoff) = pk;
            }
        asm volatile("s_waitcnt lgkmcnt(0)" ::: "memory");

        __builtin_amdgcn_s_setprio(1);
#pragma unroll
        for (int h2 = 0; h2 < 2; ++h2) {
            int rb = (c << 7) + ((h2 * 64 + g * 16) ^ ((c & 7) << 4));
            short8 pa = *reinterpret_cast<const short8*>(reinterpret_cast<char*>(pw) + rb);
#pragma unroll
            for (int dt = 0; dt < 4; ++dt) {
                short8 vf = *reinterpret_cast<const short8*>(&Vl[dt * 16 + c][h2 * 32 + g * 8]);
                acc[dt] = __builtin_amdgcn_mfma_f32_16x16x32_bf16(vf, pa, acc[dt], 0, 0, 0);
            }
        }
        __builtin_amdgcn_s_setprio(0);
    }

    float lfull = lrow + __shfl_xor(lrow, 16);
    lfull += __shfl_xor(lfull, 32);

    // partial O: [b][hh][ch][qb][q(64)][d(64)] f32; lane's q = wave*16+c, d = dt*16+4g+j
    float* po_blk = po + ((((size_t)(b * HG_ + hh) * NCH_ + ch) * (S_ / 64) + blockIdx.x) * 4096);
    const int ql = wave * 16 + c;
#pragma unroll
    for (int dt = 0; dt < 4; ++dt)
        *reinterpret_cast<f32x4*>(po_blk + ql * 64 + dt * 16 + 4 * g) = acc[dt];
    if (g == 0) {
        size_t mb = (((size_t)(b * HG_ + hh) * NCH_ + ch) * S_ + q0 + ql) * 2;
        ml[mb] = mrow;
        ml[mb + 1] = lfull;
    }
}

// ---------------- merge split-KV partials -> bf16 attn output ----------------
// grid (S/64, HG, B), 256 threads: thread t -> q = t>>2 (local), d0 = (t&3)*16.
__global__ __launch_bounds__(256) void k_attn_merge(const float* __restrict__ po,
                                                    const float* __restrict__ ml,
                                                    u16* __restrict__ out) {
    const int qb = blockIdx.x, hh = blockIdx.y, b = blockIdx.z;
    const int t = threadIdx.x;
    const int ql = t >> 2, d0 = (t & 3) * 16;
    const int q = qb * 64 + ql;

    float mv[NCH_], lv[NCH_];
    float M = -1e30f;
#pragma unroll
    for (int ch = 0; ch < NCH_; ++ch) {
        size_t mb = (((size_t)(b * HG_ + hh) * NCH_ + ch) * S_ + q) * 2;
        mv[ch] = ml[mb];
        lv[ch] = ml[mb + 1];
        M = fmaxf(M, mv[ch]);
    }
    float wch[NCH_], L = 0.f;
#pragma unroll
    for (int ch = 0; ch < NCH_; ++ch) {
        wch[ch] = __expf(mv[ch] - M);
        L += wch[ch] * lv[ch];
    }
    const float rL = 1.0f / L;

    float o[16];
#pragma unroll
    for (int i = 0; i < 16; ++i) o[i] = 0.f;
#pragma unroll
    for (int ch = 0; ch < NCH_; ++ch) {
        const float* pb = po + ((((size_t)(b * HG_ + hh) * NCH_ + ch) * (S_ / 64) + qb) * 4096) + ql * 64 + d0;
        const float w = wch[ch];
#pragma unroll
        for (int i = 0; i < 4; ++i) {
            float4 v = reinterpret_cast<const float4*>(pb)[i];
            o[4 * i + 0] += w * v.x; o[4 * i + 1] += w * v.y;
            o[4 * i + 2] += w * v.z; o[4 * i + 3] += w * v.w;
        }
    }
    ushort8v r0, r1;
#pragma unroll
    for (int i = 0; i < 8; ++i) { r0[i] = f2b(o[i] * rL); r1[i] = f2b(o[8 + i] * rL); }
    u16* op = out + (size_t)(b * S_ + q) * 1024 + (HL_ + hh) * 64 + d0;
    *reinterpret_cast<ushort8v*>(op) = r0;
    *reinterpret_cast<ushort8v*>(op + 8) = r1;
}

// ---------------- fused residual + LayerNorm (row = 1024) ----------------
__global__ __launch_bounds__(256) void k_ln(const float* __restrict__ base, const float* __restrict__ delta,
                                            const float* __restrict__ g, const float* __restrict__ bt,
                                            float* __restrict__ outf, u16* __restrict__ outb) {
    __shared__ float red[8];
    const int row = blockIdx.x, tid = threadIdx.x;
    const int lane = tid & 63, wave = tid >> 6;
    float4 xb = reinterpret_cast<const float4*>(base + (size_t)row * 1024)[tid];
    float4 xd = reinterpret_cast<const float4*>(delta + (size_t)row * 1024)[tid];
    float x0 = xb.x + xd.x, x1 = xb.y + xd.y, x2 = xb.z + xd.z, x3 = xb.w + xd.w;
    float s = x0 + x1 + x2 + x3;
#pragma unroll
    for (int off = 32; off >= 1; off >>= 1) s += __shfl_xor(s, off);
    if (lane == 0) red[wave] = s;
    __syncthreads();
    float mu = (red[0] + red[1] + red[2] + red[3]) * (1.f / 1024.f);
    float d0 = x0 - mu, d1 = x1 - mu, d2 = x2 - mu, d3 = x3 - mu;
    float s2 = d0 * d0 + d1 * d1 + d2 * d2 + d3 * d3;
#pragma unroll
    for (int off = 32; off >= 1; off >>= 1) s2 += __shfl_xor(s2, off);
    if (lane == 0) red[4 + wave] = s2;
    __syncthreads();
    float var = (red[4] + red[5] + red[6] + red[7]) * (1.f / 1024.f);
    float rs = rsqrtf(var + 1e-6f);
    float4 gv = reinterpret_cast<const float4*>(g)[tid];
    float4 bv = reinterpret_cast<const float4*>(bt)[tid];
    float o0 = d0 * rs * gv.x + bv.x;
    float o1 = d1 * rs * gv.y + bv.y;
    float o2 = d2 * rs * gv.z + bv.z;
    float o3 = d3 * rs * gv.w + bv.w;
    if (outf) {
        float4 ov; ov.x = o0; ov.y = o1; ov.z = o2; ov.w = o3;
        reinterpret_cast<float4*>(outf + (size_t)row * 1024)[tid] = ov;
    }
    if (outb) {
        ushort4v ob; ob[0] = f2b(o0); ob[1] = f2b(o1); ob[2] = f2b(o2); ob[3] = f2b(o3);
        reinterpret_cast<ushort4v*>(outb + (size_t)row * 1024)[tid] = ob;
    }
}

extern "C" void kernel_launch(void* const* d_in, const int* in_sizes, int n_in,
                              void* d_out, int out_size, void* d_ws, size_t ws_size,
                              hipStream_t stream) {
    const float* x    = (const float*)d_in[0];
    const float* mask = (const float*)d_in[1];
    const float* wq   = (const float*)d_in[2];
    const float* wq_b = (const float*)d_in[3];
    const float* wk   = (const float*)d_in[4];
    const float* wk_b = (const float*)d_in[5];
    const float* wv   = (const float*)d_in[6];
    const float* wv_b = (const float*)d_in[7];
    const float* wo   = (const float*)d_in[8];
    const float* wo_b = (const float*)d_in[9];
    const float* w1   = (const float*)d_in[10];
    const float* b1   = (const float*)d_in[11];
    const float* w2   = (const float*)d_in[12];
    const float* b2   = (const float*)d_in[13];
    const float* ln1g = (const float*)d_in[14];
    const float* ln1b = (const float*)d_in[15];
    const float* ln2g = (const float*)d_in[16];
    const float* ln2b = (const float*)d_in[17];
    float* out = (float*)d_out;

    char* ws = (char*)d_ws;
    const size_t MB = 1024ull * 1024ull;
    // P0 [0,64MB): qkv bf16 (48MB), later FFN hidden bf16 (64MB)
    u16*   qkv_b  = (u16*)(ws + 0);
    u16*   h_b    = (u16*)(ws + 0);
    // P1 [64,96MB): vT bf16 (16MB, attention phase) -> wo-out f32 / ffn2-out f32
    u16*   vTb    = (u16*)(ws + 64 * MB);
    float* ybuf   = (float*)(ws + 64 * MB);
    // P2 [96,128MB): global-attn partials (17.3MB, attention phase) -> out1 f32 (32MB)
    float* po     = (float*)(ws + 96 * MB);
    float* ml     = (float*)(ws + 113 * MB);
    float* out1   = (float*)(ws + 96 * MB);
    // P3 [128,144MB): x bf16 -> attn bf16 -> out1 bf16 (sequential lifetimes)
    u16*   xb     = (u16*)(ws + 128 * MB);
    u16*   attn_b = (u16*)(ws + 128 * MB);
    u16*   out1_b = (u16*)(ws + 128 * MB);
    // P4 [144,152MB): transposed weights bf16 (max 8MB), sequential lifetimes
    u16*   wT     = (u16*)(ws + 144 * MB);
    // P5 [152MB,+12KB): packed qkv bias f32
    float* bias3  = (float*)(ws + 152 * MB);

    const dim3 tb(256);

    // x -> bf16
    k_f32_to_bf16<<<(M_ * D_ / 4 + 255) / 256, tb, 0, stream>>>(x, xb, M_ * D_ / 4);
    // pack W_qkv^T bf16 [3072][1024] + bias
    k_transpose_bf16<<<dim3(32, 32), tb, 0, stream>>>(wq, wT, 1024, 1024, 0);
    k_transpose_bf16<<<dim3(32, 32), tb, 0, stream>>>(wk, wT, 1024, 1024, 1024);
    k_transpose_bf16<<<dim3(32, 32), tb, 0, stream>>>(wv, wT, 1024, 1024, 2048);
    k_pack_bias3<<<12, tb, 0, stream>>>(wq_b, wk_b, wv_b, bias3);
    // QKV: [8192,3072] bf16
    k_gemm<false, false, true><<<dim3(M_ / 128, 3072 / 128), tb, 0, stream>>>(
        xb, wT, bias3, nullptr, qkv_b, M_, 3072, 1024);
    // V pre-transpose for attention PV
    k_transpose_v<<<dim3(S_ / 32, 2, B_ * H_), tb, 0, stream>>>(qkv_b, vTb);
    // attention -> attn_b bf16 [B,S,H,64]
    k_attn_local<<<dim3(S_ / 64, HL_, B_), tb, 0, stream>>>(qkv_b, vTb, attn_b);
    k_attn_global_part<<<dim3(S_ / 64, HG_ * NCH_, B_), tb, 0, stream>>>(qkv_b, vTb, mask, po, ml);
    k_attn_merge<<<dim3(S_ / 64, HG_, B_), tb, 0, stream>>>(po, ml, attn_b);
    // output projection
    k_transpose_bf16<<<dim3(32, 32), tb, 0, stream>>>(wo, wT, 1024, 1024, 0);
    k_gemm<false, true, false><<<dim3(M_ / 128, 1024 / 128), tb, 0, stream>>>(
        attn_b, wT, wo_b, ybuf, nullptr, M_, 1024, 1024);
    // LN1 (residual x)
    k_ln<<<M_, tb, 0, stream>>>(x, ybuf, ln1g, ln1b, out1, out1_b);
    // FFN1 (leaky relu 0.2)
    k_transpose_bf16<<<dim3(128, 32), tb, 0, stream>>>(w1, wT, 1024, 4096, 0);
    k_gemm<true, false, true><<<dim3(M_ / 128, 4096 / 128), tb, 0, stream>>>(
        out1_b, wT, b1, nullptr, h_b, M_, 4096, 1024);
    // FFN2
    k_transpose_bf16<<<dim3(32, 128), tb, 0, stream>>>(w2, wT, 4096, 1024, 0);
    k_gemm<false, true, false><<<dim3(M_ / 128, 1024 / 128), tb, 0, stream>>>(
        h_b, wT, b2, ybuf, nullptr, M_, 1024, 4096);
    // LN2 (residual out1) -> final output f32
    k_ln<<<M_, tb, 0, stream>>>(out1, ybuf, ln2g, ln2b, out, nullptr);
}

// Round 4
// 418.999 us; speedup vs baseline: 4.3188x; 1.0348x over previous
//
#include <hip/hip_runtime.h>
#include <hip/hip_bf16.h>

typedef unsigned short u16;
typedef unsigned int u32;
typedef __attribute__((ext_vector_type(8))) short short8;
typedef __attribute__((ext_vector_type(8))) unsigned short ushort8v;
typedef __attribute__((ext_vector_type(4))) unsigned short ushort4v;
typedef __attribute__((ext_vector_type(4))) float f32x4;

static constexpr int B_ = 2, S_ = 4096, D_ = 1024, H_ = 16, HG_ = 2, W_ = 128, DFF_ = 4096;
static constexpr int HL_ = H_ - HG_;   // 14 local heads
static constexpr int M_ = B_ * S_;     // 8192 rows
static constexpr int NCH_ = 4;         // KV chunks for global-head split

static __device__ __forceinline__ u16 f2b(float f) {
    u32 u = __builtin_bit_cast(u32, f);
    u32 r = (u + 0x7fffu + ((u >> 16) & 1u)) >> 16;   // RNE
    return (u16)r;
}
static __device__ __forceinline__ float b2f(u16 b) {
    return __builtin_bit_cast(float, (u32)b << 16);
}

// ---------------- f32 -> bf16 convert (vectorized) ----------------
__global__ __launch_bounds__(256) void k_f32_to_bf16(const float* __restrict__ src,
                                                     u16* __restrict__ dst, int n4) {
    int i = blockIdx.x * 256 + threadIdx.x;
    if (i >= n4) return;
    float4 v = reinterpret_cast<const float4*>(src)[i];
    ushort4v o; o[0] = f2b(v.x); o[1] = f2b(v.y); o[2] = f2b(v.z); o[3] = f2b(v.w);
    reinterpret_cast<ushort4v*>(dst)[i] = o;
}

// ---------------- weight transpose+convert: W[K][N] f32 -> WT[ro+N][K] bf16 ----------------
__global__ __launch_bounds__(256) void k_transpose_bf16(const float* __restrict__ src,
                                                        u16* __restrict__ dst,
                                                        int K, int N, int ro) {
    __shared__ float tile[32][33];
    const int tx = threadIdx.x & 31, ty = threadIdx.x >> 5;  // 32x8
    const int bx = blockIdx.x, by = blockIdx.y;
#pragma unroll
    for (int jj = 0; jj < 4; ++jj) {
        int kk = by * 32 + ty + jj * 8;
        int nn = bx * 32 + tx;
        tile[ty + jj * 8][tx] = src[(size_t)kk * N + nn];
    }
    __syncthreads();
#pragma unroll
    for (int jj = 0; jj < 4; ++jj) {
        int nn = bx * 32 + ty + jj * 8;
        int kk = by * 32 + tx;
        dst[(size_t)(ro + nn) * K + kk] = f2b(tile[tx][ty + jj * 8]);
    }
}

// ---------------- V transpose: qkv V-cols -> vT[(b*H+h)*64 + d][S] bf16 ----------------
__global__ __launch_bounds__(256) void k_transpose_v(const u16* __restrict__ qkv,
                                                     u16* __restrict__ vT) {
    __shared__ u16 tile[32][33];
    const int tx = threadIdx.x & 31, ty = threadIdx.x >> 5;  // 32x8
    const int s0 = blockIdx.x * 32;
    const int d0 = blockIdx.y * 32;
    const int bh = blockIdx.z;
    const int b = bh >> 4, h = bh & 15;
#pragma unroll
    for (int jj = 0; jj < 4; ++jj) {
        int srow = s0 + ty + jj * 8;
        tile[ty + jj * 8][tx] = qkv[(size_t)(b * S_ + srow) * 3072 + 2048 + h * 64 + d0 + tx];
    }
    __syncthreads();
#pragma unroll
    for (int jj = 0; jj < 4; ++jj) {
        int d = d0 + ty + jj * 8;
        vT[(size_t)((b * H_ + h) * 64 + d) * S_ + s0 + tx] = tile[tx][ty + jj * 8];
    }
}

__global__ void k_pack_bias3(const float* __restrict__ a, const float* __restrict__ b,
                             const float* __restrict__ c, float* __restrict__ dst) {
    int i = blockIdx.x * 256 + threadIdx.x;
    if (i >= 3072) return;
    dst[i] = i < 1024 ? a[i] : (i < 2048 ? b[i - 1024] : c[i - 2048]);
}

#define GLDS16(gp, lp) __builtin_amdgcn_global_load_lds( \
    (const __attribute__((address_space(1))) void*)(gp),  \
    (__attribute__((address_space(3))) void*)(lp), 16, 0, 0)

template <int N>
static __device__ __forceinline__ void vwait() {
    if constexpr (N == 0) asm volatile("s_waitcnt vmcnt(0)" ::: "memory");
    else if constexpr (N == 3) asm volatile("s_waitcnt vmcnt(3)" ::: "memory");
    else asm volatile("s_waitcnt vmcnt(4)" ::: "memory");
    __builtin_amdgcn_sched_barrier(0);
}

// ---------------- 8-phase bf16 MFMA GEMM: C[M,N] = A[M,K] @ Bt[N,K]^T + bias ----------------
// BMx256 tile, BK=64, 512 thr = 8 waves (2M x 4N). K-half phase split, counted vmcnt,
// st_16x32 LDS swizzle via pre-swizzled global source + swizzled ds_read (linear LDS dest).
template <int BM, bool LEAKY, bool OUTF, bool OUTB>
__global__ __launch_bounds__(512, 2) void k_gemm8(const u16* __restrict__ A, const u16* __restrict__ Bt,
                                                  const float* __restrict__ bias,
                                                  float* __restrict__ Cf, u16* __restrict__ Cb,
                                                  int M, int N, int K) {
    constexpr int MR = BM / 32;            // m-frags per wave
    constexpr int LA = BM / 128;           // global_load_lds per A K-half per wave (1 or 2)
    constexpr int AHALF = BM * 64;         // bytes per A K-half tile (BM x 32 bf16)
    constexpr int ABUF = 2 * AHALF;
    constexpr int BHALF = 16384;           // 256 x 32 bf16
    constexpr int PARSZ = ABUF + 2 * BHALF;
    constexpr int NWT = LA + 2;            // steady-state vmcnt (newest A-half + B-half in flight)

    __shared__ __align__(16) char smem[2 * PARSZ];

    const int tid = threadIdx.x;
    const int lane = tid & 63, w = tid >> 6;
    const int wm = w >> 2, wn = w & 3;     // 2 x 4 waves
    const int c = lane & 15, g = lane >> 4;

    // T1: bijective XCD swizzle on x-fastest linearized block id
    const int GX = gridDim.x;
    const int nwg = GX * gridDim.y;
    const int lin = blockIdx.y * GX + blockIdx.x;
    const int qq = nwg >> 3, rm = nwg & 7;
    const int xcd = lin & 7, idx = lin >> 3;
    const int wg = (xcd < rm ? xcd * (qq + 1) : rm * (qq + 1) + (xcd - rm) * qq) + idx;
    const int m0 = (wg % GX) * BM;
    const int n0 = (wg / GX) * 256;

    // staging source coords (inverse st_16x32 swizzle): linear LDS granule (w,lane) pulls
    // row = st*16 + (lane>>2), k-granule = (lane&3) ^ ((lane>=32)?2:0)
    const int srr = lane >> 2;
    const int sgc = (lane & 3) ^ ((lane >> 4) & 2);
    const u16* gA0 = A + (size_t)(m0 + w * 16 + srr) * K + sgc * 8;
    const u16* gA1 = (LA == 2) ? (A + (size_t)(m0 + 128 + w * 16 + srr) * K + sgc * 8) : gA0;
    const u16* gB0 = Bt + (size_t)(n0 + w * 16 + srr) * K + sgc * 8;
    const u16* gB1 = Bt + (size_t)(n0 + 128 + w * 16 + srr) * K + sgc * 8;

#define STG_A(par, kh, kt) do { \
        char* _d = smem + (par) * PARSZ + (kh) * AHALF + w * 1024; \
        GLDS16(gA0 + (size_t)(kt) * 64 + (kh) * 32, _d); \
        if (LA == 2) GLDS16(gA1 + (size_t)(kt) * 64 + (kh) * 32, _d + 8192); \
    } while (0)
#define STG_B(par, kh, kt) do { \
        char* _d = smem + (par) * PARSZ + ABUF + (kh) * BHALF + w * 1024; \
        GLDS16(gB0 + (size_t)(kt) * 64 + (kh) * 32, _d); \
        GLDS16(gB1 + (size_t)(kt) * 64 + (kh) * 32, _d + 8192); \
    } while (0)

    // swizzled ds_read byte offset within a (row16 x k32) subtile row
    const int gb = (g ^ ((c >> 3) << 1)) * 16;
    const int arow = c * 64 + gb;

    f32x4 acc[MR][4];
#pragma unroll
    for (int i = 0; i < MR; ++i)
#pragma unroll
        for (int j = 0; j < 4; ++j)
#pragma unroll
            for (int e = 0; e < 4; ++e) acc[i][j][e] = 0.f;

    // prologue: fully stage K-tile 0, drain once
    STG_A(0, 0, 0); STG_B(0, 0, 0); STG_A(0, 1, 0); STG_B(0, 1, 0);
    vwait<0>();
    __builtin_amdgcn_s_barrier();

    const int NK = K >> 6;
    short8 af[MR], b0, b1;
    for (int kt = 0; kt < NK; ++kt) {
        const int par = kt & 1, nxt = par ^ 1;
        const char* bp = smem + par * PARSZ;
        const bool more = (kt + 1) < NK;
        // ---- phase 1: ks=0, n-frags 0/1; stage A-Kh0(kt+1)
#pragma unroll
        for (int mi = 0; mi < MR; ++mi)
            af[mi] = *reinterpret_cast<const short8*>(bp + (wm * MR + mi) * 1024 + arow);
        b0 = *reinterpret_cast<const short8*>(bp + ABUF + (wn * 4 + 0) * 1024 + arow);
        b1 = *reinterpret_cast<const short8*>(bp + ABUF + (wn * 4 + 1) * 1024 + arow);
        if (more) STG_A(nxt, 0, kt + 1);
        __builtin_amdgcn_s_barrier();
        __builtin_amdgcn_s_setprio(1);
#pragma unroll
        for (int mi = 0; mi < MR; ++mi) {
            acc[mi][0] = __builtin_amdgcn_mfma_f32_16x16x32_bf16(af[mi], b0, acc[mi][0], 0, 0, 0);
            acc[mi][1] = __builtin_amdgcn_mfma_f32_16x16x32_bf16(af[mi], b1, acc[mi][1], 0, 0, 0);
        }
        __builtin_amdgcn_s_setprio(0);
        __builtin_amdgcn_s_barrier();
        // ---- phase 2: ks=0, n-frags 2/3; stage B-Kh0(kt+1)
        b0 = *reinterpret_cast<const short8*>(bp + ABUF + (wn * 4 + 2) * 1024 + arow);
        b1 = *reinterpret_cast<const short8*>(bp + ABUF + (wn * 4 + 3) * 1024 + arow);
        if (more) STG_B(nxt, 0, kt + 1);
        __builtin_amdgcn_s_barrier();
        __builtin_amdgcn_s_setprio(1);
#pragma unroll
        for (int mi = 0; mi < MR; ++mi) {
            acc[mi][2] = __builtin_amdgcn_mfma_f32_16x16x32_bf16(af[mi], b0, acc[mi][2], 0, 0, 0);
            acc[mi][3] = __builtin_amdgcn_mfma_f32_16x16x32_bf16(af[mi], b1, acc[mi][3], 0, 0, 0);
        }
        __builtin_amdgcn_s_setprio(0);
        if (more) vwait<NWT>(); else vwait<0>();   // K-half boundary: Kh1(kt) staged >=4 phases ago
        __builtin_amdgcn_s_barrier();
        // ---- phase 3: ks=1, n-frags 0/1; stage A-Kh1(kt+1)
#pragma unroll
        for (int mi = 0; mi < MR; ++mi)
            af[mi] = *reinterpret_cast<const short8*>(bp + AHALF + (wm * MR + mi) * 1024 + arow);
        b0 = *reinterpret_cast<const short8*>(bp + ABUF + BHALF + (wn * 4 + 0) * 1024 + arow);
        b1 = *reinterpret_cast<const short8*>(bp + ABUF + BHALF + (wn * 4 + 1) * 1024 + arow);
        if (more) STG_A(nxt, 1, kt + 1);
        __builtin_amdgcn_s_barrier();
        __builtin_amdgcn_s_setprio(1);
#pragma unroll
        for (int mi = 0; mi < MR; ++mi) {
            acc[mi][0] = __builtin_amdgcn_mfma_f32_16x16x32_bf16(af[mi], b0, acc[mi][0], 0, 0, 0);
            acc[mi][1] = __builtin_amdgcn_mfma_f32_16x16x32_bf16(af[mi], b1, acc[mi][1], 0, 0, 0);
        }
        __builtin_amdgcn_s_setprio(0);
        __builtin_amdgcn_s_barrier();
        // ---- phase 4: ks=1, n-frags 2/3; stage B-Kh1(kt+1)
        b0 = *reinterpret_cast<const short8*>(bp + ABUF + BHALF + (wn * 4 + 2) * 1024 + arow);
        b1 = *reinterpret_cast<const short8*>(bp + ABUF + BHALF + (wn * 4 + 3) * 1024 + arow);
        if (more) STG_B(nxt, 1, kt + 1);
        __builtin_amdgcn_s_barrier();
        __builtin_amdgcn_s_setprio(1);
#pragma unroll
        for (int mi = 0; mi < MR; ++mi) {
            acc[mi][2] = __builtin_amdgcn_mfma_f32_16x16x32_bf16(af[mi], b0, acc[mi][2], 0, 0, 0);
            acc[mi][3] = __builtin_amdgcn_mfma_f32_16x16x32_bf16(af[mi], b1, acc[mi][3], 0, 0, 0);
        }
        __builtin_amdgcn_s_setprio(0);
        if (more) vwait<NWT>();                    // K-tile boundary: Kh0(kt+1) staged at p1/p2
        __builtin_amdgcn_s_barrier();
    }

#pragma unroll
    for (int mi = 0; mi < MR; ++mi) {
        const int rowb = m0 + wm * (BM / 2) + mi * 16 + g * 4;
#pragma unroll
        for (int ni = 0; ni < 4; ++ni) {
            const int col = n0 + wn * 64 + ni * 16 + c;
            const float bs = bias[col];
#pragma unroll
            for (int j = 0; j < 4; ++j) {
                float v = acc[mi][ni][j] + bs;
                if (LEAKY) v = v > 0.f ? v : 0.2f * v;
                const size_t idxo = (size_t)(rowb + j) * N + col;
                if (OUTF) Cf[idxo] = v;
                if (OUTB) Cb[idxo] = f2b(v);
            }
        }
    }
#undef STG_A
#undef STG_B
}

// ---------------- MFMA flash attention, LOCAL (banded) heads ----------------
__global__ __launch_bounds__(256) void k_attn_local(const u16* __restrict__ qkv,
                                                    const u16* __restrict__ vT,
                                                    u16* __restrict__ out) {
    __shared__ __align__(16) u16 Kl[64][72];
    __shared__ __align__(16) u16 Vl[64][72];
    __shared__ __align__(16) u16 Pl[4][1024];
    const int tid = threadIdx.x, lane = tid & 63, wave = tid >> 6;
    const int c = lane & 15, g = lane >> 4;
    const int b = blockIdx.z, h = blockIdx.y;
    const int q0 = blockIdx.x * 64;
    const int qrow = q0 + wave * 16 + c;

    short8 qf[2];
    {
        const u16* qp = qkv + (size_t)(b * S_ + qrow) * 3072 + h * 64 + g * 8;
        qf[0] = *reinterpret_cast<const short8*>(qp);
        qf[1] = *reinterpret_cast<const short8*>(qp + 32);
    }

    f32x4 acc[4];
#pragma unroll
    for (int dt = 0; dt < 4; ++dt)
#pragma unroll
        for (int j = 0; j < 4; ++j) acc[dt][j] = 0.f;
    float mrow = -1e30f, lrow = 0.f;

    const int t_lo = max(0, q0 - W_) >> 6;
    const int t_hi = min(S_ - 1, q0 + 63 + W_) >> 6;
    u16* pw = Pl[wave];

    for (int t = t_lo; t <= t_hi; ++t) {
        __syncthreads();
#pragma unroll
        for (int it = 0; it < 2; ++it) {
            int L = it * 256 + tid;
            int r = L >> 3, cb = (L & 7) * 8;
            *reinterpret_cast<ushort8v*>(&Kl[r][cb]) =
                *reinterpret_cast<const ushort8v*>(&qkv[(size_t)(b * S_ + t * 64 + r) * 3072 + 1024 + h * 64 + cb]);
            *reinterpret_cast<ushort8v*>(&Vl[r][cb]) =
                *reinterpret_cast<const ushort8v*>(&vT[(size_t)((b * H_ + h) * 64 + r) * S_ + t * 64 + cb]);
        }
        __syncthreads();

        f32x4 s[4];
#pragma unroll
        for (int nt = 0; nt < 4; ++nt)
#pragma unroll
            for (int j = 0; j < 4; ++j) s[nt][j] = 0.f;
        __builtin_amdgcn_s_setprio(1);
#pragma unroll
        for (int kc = 0; kc < 2; ++kc) {
#pragma unroll
            for (int nt = 0; nt < 4; ++nt) {
                short8 kf = *reinterpret_cast<const short8*>(&Kl[nt * 16 + c][kc * 32 + g * 8]);
                s[nt] = __builtin_amdgcn_mfma_f32_16x16x32_bf16(kf, qf[kc], s[nt], 0, 0, 0);
            }
        }
        __builtin_amdgcn_s_setprio(0);

        float p[4][4];
        float tmax = -1e30f;
#pragma unroll
        for (int nt = 0; nt < 4; ++nt)
#pragma unroll
            for (int j = 0; j < 4; ++j) {
                float sv = s[nt][j] * 0.125f;
                int key = t * 64 + nt * 16 + 4 * g + j;
                bool val = (key >= qrow - W_) && (key <= qrow + W_);
                sv = val ? sv : -1e30f;
                p[nt][j] = sv;
                tmax = fmaxf(tmax, sv);
            }
        tmax = fmaxf(tmax, __shfl_xor(tmax, 16));
        tmax = fmaxf(tmax, __shfl_xor(tmax, 32));
        float mnew = fmaxf(mrow, tmax);
        float fac = __expf(mrow - mnew);
        mrow = mnew;
        float psum = 0.f;
#pragma unroll
        for (int nt = 0; nt < 4; ++nt)
#pragma unroll
            for (int j = 0; j < 4; ++j) {
                p[nt][j] = __expf(p[nt][j] - mnew);
                psum += p[nt][j];
            }
        lrow = lrow * fac + psum;
#pragma unroll
        for (int dt = 0; dt < 4; ++dt)
#pragma unroll
            for (int j = 0; j < 4; ++j) acc[dt][j] *= fac;

#pragma unroll
        for (int nt = 0; nt < 4; ++nt)
#pragma unroll
            for (int jp = 0; jp < 2; ++jp) {
                u32 pk = (u32)f2b(p[nt][2 * jp]) | ((u32)f2b(p[nt][2 * jp + 1]) << 16);
                int byteoff = (c << 7) + ((nt * 32 + 8 * g + 4 * jp) ^ ((c & 7) << 4));
                *reinterpret_cast<u32*>(reinterpret_cast<char*>(pw) + byteoff) = pk;
            }
        asm volatile("s_waitcnt lgkmcnt(0)" ::: "memory");

        __builtin_amdgcn_s_setprio(1);
#pragma unroll
        for (int h2 = 0; h2 < 2; ++h2) {
            int rb = (c << 7) + ((h2 * 64 + g * 16) ^ ((c & 7) << 4));
            short8 pa = *reinterpret_cast<const short8*>(reinterpret_cast<char*>(pw) + rb);
#pragma unroll
            for (int dt = 0; dt < 4; ++dt) {
                short8 vf = *reinterpret_cast<const short8*>(&Vl[dt * 16 + c][h2 * 32 + g * 8]);
                acc[dt] = __builtin_amdgcn_mfma_f32_16x16x32_bf16(vf, pa, acc[dt], 0, 0, 0);
            }
        }
        __builtin_amdgcn_s_setprio(0);
    }

    float lfull = lrow + __shfl_xor(lrow, 16);
    lfull += __shfl_xor(lfull, 32);
    const float rinv = 1.0f / lfull;

#pragma unroll
    for (int dt = 0; dt < 4; ++dt) {
        u32 w0 = (u32)f2b(acc[dt][0] * rinv) | ((u32)f2b(acc[dt][1] * rinv) << 16);
        u32 w1 = (u32)f2b(acc[dt][2] * rinv) | ((u32)f2b(acc[dt][3] * rinv) << 16);
        uint2 wv; wv.x = w0; wv.y = w1;
        *reinterpret_cast<uint2*>(out + (size_t)(b * S_ + qrow) * 1024 + h * 64 + dt * 16 + 4 * g) = wv;
    }
}

// ---------------- GLOBAL heads: split-KV partial flash ----------------
__global__ __launch_bounds__(256) void k_attn_global_part(const u16* __restrict__ qkv,
                                                          const u16* __restrict__ vT,
                                                          const float* __restrict__ mask,
                                                          float* __restrict__ po,
                                                          float* __restrict__ ml) {
    __shared__ __align__(16) u16 Kl[64][72];
    __shared__ __align__(16) u16 Vl[64][72];
    __shared__ __align__(16) u16 Pl[4][1024];
    __shared__ float maskl[64];
    const int tid = threadIdx.x, lane = tid & 63, wave = tid >> 6;
    const int c = lane & 15, g = lane >> 4;
    const int b = blockIdx.z;
    const int hh = blockIdx.y >> 2, ch = blockIdx.y & 3;
    const int h = HL_ + hh;
    const int q0 = blockIdx.x * 64;
    const int qrow = q0 + wave * 16 + c;

    short8 qf[2];
    {
        const u16* qp = qkv + (size_t)(b * S_ + qrow) * 3072 + h * 64 + g * 8;
        qf[0] = *reinterpret_cast<const short8*>(qp);
        qf[1] = *reinterpret_cast<const short8*>(qp + 32);
    }

    f32x4 acc[4];
#pragma unroll
    for (int dt = 0; dt < 4; ++dt)
#pragma unroll
        for (int j = 0; j < 4; ++j) acc[dt][j] = 0.f;
    float mrow = -1e30f, lrow = 0.f;
    u16* pw = Pl[wave];

    const int t_lo = ch * (S_ / 64 / NCH_), t_hi = t_lo + (S_ / 64 / NCH_) - 1;
    for (int t = t_lo; t <= t_hi; ++t) {
        __syncthreads();
#pragma unroll
        for (int it = 0; it < 2; ++it) {
            int L = it * 256 + tid;
            int r = L >> 3, cb = (L & 7) * 8;
            *reinterpret_cast<ushort8v*>(&Kl[r][cb]) =
                *reinterpret_cast<const ushort8v*>(&qkv[(size_t)(b * S_ + t * 64 + r) * 3072 + 1024 + h * 64 + cb]);
            *reinterpret_cast<ushort8v*>(&Vl[r][cb]) =
                *reinterpret_cast<const ushort8v*>(&vT[(size_t)((b * H_ + h) * 64 + r) * S_ + t * 64 + cb]);
        }
        if (tid < 64) maskl[tid] = mask[b * S_ + t * 64 + tid] * (-1000.0f);
        __syncthreads();

        f32x4 s[4];
#pragma unroll
        for (int nt = 0; nt < 4; ++nt)
#pragma unroll
            for (int j = 0; j < 4; ++j) s[nt][j] = 0.f;
        __builtin_amdgcn_s_setprio(1);
#pragma unroll
        for (int kc = 0; kc < 2; ++kc) {
#pragma unroll
            for (int nt = 0; nt < 4; ++nt) {
                short8 kf = *reinterpret_cast<const short8*>(&Kl[nt * 16 + c][kc * 32 + g * 8]);
                s[nt] = __builtin_amdgcn_mfma_f32_16x16x32_bf16(kf, qf[kc], s[nt], 0, 0, 0);
            }
        }
        __builtin_amdgcn_s_setprio(0);

        float p[4][4];
        float tmax = -1e30f;
#pragma unroll
        for (int nt = 0; nt < 4; ++nt)
#pragma unroll
            for (int j = 0; j < 4; ++j) {
                float sv = s[nt][j] * 0.125f + maskl[nt * 16 + 4 * g + j];
                p[nt][j] = sv;
                tmax = fmaxf(tmax, sv);
            }
        tmax = fmaxf(tmax, __shfl_xor(tmax, 16));
        tmax = fmaxf(tmax, __shfl_xor(tmax, 32));
        float mnew = fmaxf(mrow, tmax);
        float fac = __expf(mrow - mnew);
        mrow = mnew;
        float psum = 0.f;
#pragma unroll
        for (int nt = 0; nt < 4; ++nt)
#pragma unroll
            for (int j = 0; j < 4; ++j) {
                p[nt][j] = __expf(p[nt][j] - mnew);
                psum += p[nt][j];
            }
        lrow = lrow * fac + psum;
#pragma unroll
        for (int dt = 0; dt < 4; ++dt)
#pragma unroll
            for (int j = 0; j < 4; ++j) acc[dt][j] *= fac;

#pragma unroll
        for (int nt = 0; nt < 4; ++nt)
#pragma unroll
            for (int jp = 0; jp < 2; ++jp) {
                u32 pk = (u32)f2b(p[nt][2 * jp]) | ((u32)f2b(p[nt][2 * jp + 1]) << 16);
                int byteoff = (c << 7) + ((nt * 32 + 8 * g + 4 * jp) ^ ((c & 7) << 4));
                *reinterpret_cast<u32*>(reinterpret_cast<char*>(pw) + byteoff) = pk;
            }
        asm volatile("s_waitcnt lgkmcnt(0)" ::: "memory");

        __builtin_amdgcn_s_setprio(1);
#pragma unroll
        for (int h2 = 0; h2 < 2; ++h2) {
            int rb = (c << 7) + ((h2 * 64 + g * 16) ^ ((c & 7) << 4));
            short8 pa = *reinterpret_cast<const short8*>(reinterpret_cast<char*>(pw) + rb);
#pragma unroll
            for (int dt = 0; dt < 4; ++dt) {
                short8 vf = *reinterpret_cast<const short8*>(&Vl[dt * 16 + c][h2 * 32 + g * 8]);
                acc[dt] = __builtin_amdgcn_mfma_f32_16x16x32_bf16(vf, pa, acc[dt], 0, 0, 0);
            }
        }
        __builtin_amdgcn_s_setprio(0);
    }

    float lfull = lrow + __shfl_xor(lrow, 16);
    lfull += __shfl_xor(lfull, 32);

    float* po_blk = po + ((((size_t)(b * HG_ + hh) * NCH_ + ch) * (S_ / 64) + blockIdx.x) * 4096);
    const int ql = wave * 16 + c;
#pragma unroll
    for (int dt = 0; dt < 4; ++dt)
        *reinterpret_cast<f32x4*>(po_blk + ql * 64 + dt * 16 + 4 * g) = acc[dt];
    if (g == 0) {
        size_t mb = (((size_t)(b * HG_ + hh) * NCH_ + ch) * S_ + q0 + ql) * 2;
        ml[mb] = mrow;
        ml[mb + 1] = lfull;
    }
}

// ---------------- merge split-KV partials -> bf16 attn output ----------------
__global__ __launch_bounds__(256) void k_attn_merge(const float* __restrict__ po,
                                                    const float* __restrict__ ml,
                                                    u16* __restrict__ out) {
    const int qb = blockIdx.x, hh = blockIdx.y, b = blockIdx.z;
    const int t = threadIdx.x;
    const int ql = t >> 2, d0 = (t & 3) * 16;
    const int q = qb * 64 + ql;

    float mv[NCH_], lv[NCH_];
    float M = -1e30f;
#pragma unroll
    for (int ch = 0; ch < NCH_; ++ch) {
        size_t mb = (((size_t)(b * HG_ + hh) * NCH_ + ch) * S_ + q) * 2;
        mv[ch] = ml[mb];
        lv[ch] = ml[mb + 1];
        M = fmaxf(M, mv[ch]);
    }
    float wch[NCH_], L = 0.f;
#pragma unroll
    for (int ch = 0; ch < NCH_; ++ch) {
        wch[ch] = __expf(mv[ch] - M);
        L += wch[ch] * lv[ch];
    }
    const float rL = 1.0f / L;

    float o[16];
#pragma unroll
    for (int i = 0; i < 16; ++i) o[i] = 0.f;
#pragma unroll
    for (int ch = 0; ch < NCH_; ++ch) {
        const float* pb = po + ((((size_t)(b * HG_ + hh) * NCH_ + ch) * (S_ / 64) + qb) * 4096) + ql * 64 + d0;
        const float w = wch[ch];
#pragma unroll
        for (int i = 0; i < 4; ++i) {
            float4 v = reinterpret_cast<const float4*>(pb)[i];
            o[4 * i + 0] += w * v.x; o[4 * i + 1] += w * v.y;
            o[4 * i + 2] += w * v.z; o[4 * i + 3] += w * v.w;
        }
    }
    ushort8v r0, r1;
#pragma unroll
    for (int i = 0; i < 8; ++i) { r0[i] = f2b(o[i] * rL); r1[i] = f2b(o[8 + i] * rL); }
    u16* op = out + (size_t)(b * S_ + q) * 1024 + (HL_ + hh) * 64 + d0;
    *reinterpret_cast<ushort8v*>(op) = r0;
    *reinterpret_cast<ushort8v*>(op + 8) = r1;
}

// ---------------- fused residual + LayerNorm (row = 1024) ----------------
__global__ __launch_bounds__(256) void k_ln(const float* __restrict__ base, const float* __restrict__ delta,
                                            const float* __restrict__ g, const float* __restrict__ bt,
                                            float* __restrict__ outf, u16* __restrict__ outb) {
    __shared__ float red[8];
    const int row = blockIdx.x, tid = threadIdx.x;
    const int lane = tid & 63, wave = tid >> 6;
    float4 xb = reinterpret_cast<const float4*>(base + (size_t)row * 1024)[tid];
    float4 xd = reinterpret_cast<const float4*>(delta + (size_t)row * 1024)[tid];
    float x0 = xb.x + xd.x, x1 = xb.y + xd.y, x2 = xb.z + xd.z, x3 = xb.w + xd.w;
    float s = x0 + x1 + x2 + x3;
#pragma unroll
    for (int off = 32; off >= 1; off >>= 1) s += __shfl_xor(s, off);
    if (lane == 0) red[wave] = s;
    __syncthreads();
    float mu = (red[0] + red[1] + red[2] + red[3]) * (1.f / 1024.f);
    float d0 = x0 - mu, d1 = x1 - mu, d2 = x2 - mu, d3 = x3 - mu;
    float s2 = d0 * d0 + d1 * d1 + d2 * d2 + d3 * d3;
#pragma unroll
    for (int off = 32; off >= 1; off >>= 1) s2 += __shfl_xor(s2, off);
    if (lane == 0) red[4 + wave] = s2;
    __syncthreads();
    float var = (red[4] + red[5] + red[6] + red[7]) * (1.f / 1024.f);
    float rs = rsqrtf(var + 1e-6f);
    float4 gv = reinterpret_cast<const float4*>(g)[tid];
    float4 bv = reinterpret_cast<const float4*>(bt)[tid];
    float o0 = d0 * rs * gv.x + bv.x;
    float o1 = d1 * rs * gv.y + bv.y;
    float o2 = d2 * rs * gv.z + bv.z;
    float o3 = d3 * rs * gv.w + bv.w;
    if (outf) {
        float4 ov; ov.x = o0; ov.y = o1; ov.z = o2; ov.w = o3;
        reinterpret_cast<float4*>(outf + (size_t)row * 1024)[tid] = ov;
    }
    if (outb) {
        ushort4v ob; ob[0] = f2b(o0); ob[1] = f2b(o1); ob[2] = f2b(o2); ob[3] = f2b(o3);
        reinterpret_cast<ushort4v*>(outb + (size_t)row * 1024)[tid] = ob;
    }
}

extern "C" void kernel_launch(void* const* d_in, const int* in_sizes, int n_in,
                              void* d_out, int out_size, void* d_ws, size_t ws_size,
                              hipStream_t stream) {
    const float* x    = (const float*)d_in[0];
    const float* mask = (const float*)d_in[1];
    const float* wq   = (const float*)d_in[2];
    const float* wq_b = (const float*)d_in[3];
    const float* wk   = (const float*)d_in[4];
    const float* wk_b = (const float*)d_in[5];
    const float* wv   = (const float*)d_in[6];
    const float* wv_b = (const float*)d_in[7];
    const float* wo   = (const float*)d_in[8];
    const float* wo_b = (const float*)d_in[9];
    const float* w1   = (const float*)d_in[10];
    const float* b1   = (const float*)d_in[11];
    const float* w2   = (const float*)d_in[12];
    const float* b2   = (const float*)d_in[13];
    const float* ln1g = (const float*)d_in[14];
    const float* ln1b = (const float*)d_in[15];
    const float* ln2g = (const float*)d_in[16];
    const float* ln2b = (const float*)d_in[17];
    float* out = (float*)d_out;

    char* ws = (char*)d_ws;
    const size_t MB = 1024ull * 1024ull;
    u16*   qkv_b  = (u16*)(ws + 0);
    u16*   h_b    = (u16*)(ws + 0);
    u16*   vTb    = (u16*)(ws + 64 * MB);
    float* ybuf   = (float*)(ws + 64 * MB);
    float* po     = (float*)(ws + 96 * MB);
    float* ml     = (float*)(ws + 113 * MB);
    float* out1   = (float*)(ws + 96 * MB);
    u16*   xb     = (u16*)(ws + 128 * MB);
    u16*   attn_b = (u16*)(ws + 128 * MB);
    u16*   out1_b = (u16*)(ws + 128 * MB);
    u16*   wT     = (u16*)(ws + 144 * MB);
    float* bias3  = (float*)(ws + 152 * MB);

    const dim3 tb(256);
    const dim3 tg(512);

    // x -> bf16
    k_f32_to_bf16<<<(M_ * D_ / 4 + 255) / 256, tb, 0, stream>>>(x, xb, M_ * D_ / 4);
    // pack W_qkv^T bf16 [3072][1024] + bias
    k_transpose_bf16<<<dim3(32, 32), tb, 0, stream>>>(wq, wT, 1024, 1024, 0);
    k_transpose_bf16<<<dim3(32, 32), tb, 0, stream>>>(wk, wT, 1024, 1024, 1024);
    k_transpose_bf16<<<dim3(32, 32), tb, 0, stream>>>(wv, wT, 1024, 1024, 2048);
    k_pack_bias3<<<12, tb, 0, stream>>>(wq_b, wk_b, wv_b, bias3);
    // QKV: [8192,3072] bf16
    k_gemm8<256, false, false, true><<<dim3(M_ / 256, 3072 / 256), tg, 0, stream>>>(
        xb, wT, bias3, nullptr, qkv_b, M_, 3072, 1024);
    // V pre-transpose for attention PV
    k_transpose_v<<<dim3(S_ / 32, 2, B_ * H_), tb, 0, stream>>>(qkv_b, vTb);
    // attention -> attn_b bf16 [B,S,H,64]
    k_attn_local<<<dim3(S_ / 64, HL_, B_), tb, 0, stream>>>(qkv_b, vTb, attn_b);
    k_attn_global_part<<<dim3(S_ / 64, HG_ * NCH_, B_), tb, 0, stream>>>(qkv_b, vTb, mask, po, ml);
    k_attn_merge<<<dim3(S_ / 64, HG_, B_), tb, 0, stream>>>(po, ml, attn_b);
    // output projection (N=1024 -> BM=128 keeps grid at 256 blocks)
    k_transpose_bf16<<<dim3(32, 32), tb, 0, stream>>>(wo, wT, 1024, 1024, 0);
    k_gemm8<128, false, true, false><<<dim3(M_ / 128, 1024 / 256), tg, 0, stream>>>(
        attn_b, wT, wo_b, ybuf, nullptr, M_, 1024, 1024);
    // LN1 (residual x)
    k_ln<<<M_, tb, 0, stream>>>(x, ybuf, ln1g, ln1b, out1, out1_b);
    // FFN1 (leaky relu 0.2)
    k_transpose_bf16<<<dim3(128, 32), tb, 0, stream>>>(w1, wT, 1024, 4096, 0);
    k_gemm8<256, true, false, true><<<dim3(M_ / 256, 4096 / 256), tg, 0, stream>>>(
        out1_b, wT, b1, nullptr, h_b, M_, 4096, 1024);
    // FFN2
    k_transpose_bf16<<<dim3(32, 128), tb, 0, stream>>>(w2, wT, 4096, 1024, 0);
    k_gemm8<128, false, true, false><<<dim3(M_ / 128, 1024 / 256), tg, 0, stream>>>(
        h_b, wT, b2, ybuf, nullptr, M_, 1024, 4096);
    // LN2 (residual out1) -> final output f32
    k_ln<<<M_, tb, 0, stream>>>(out1, ybuf, ln2g, ln2b, out, nullptr);
}